// Round 7
// baseline (1483.632 us; speedup 1.0000x reference)
//
#include <hip/hip_runtime.h>
#include <stdint.h>

#define DIM 128

static inline int cdiv(long a, long b) { return (int)((a + b - 1) / b); }

// clang ext-vector types: __builtin_nontemporal_* requires real vector types.
typedef float f32x4 __attribute__((ext_vector_type(4)));

// ---- bf16 pack/unpack (RNE) ----
__device__ __forceinline__ unsigned pk_bf16(float a, float b) {
  unsigned ua = __float_as_uint(a), ub = __float_as_uint(b);
  ua = (ua + 0x7FFFu + ((ua >> 16) & 1u)) >> 16;
  ub = (ub + 0x7FFFu + ((ub >> 16) & 1u)) >> 16;
  return ua | (ub << 16);
}
__device__ __forceinline__ float bf_lo(unsigned u) { return __uint_as_float(u << 16); }
__device__ __forceinline__ float bf_hi(unsigned u) { return __uint_as_float(u & 0xFFFF0000u); }

// Merged index-convert + degree-count: reads raw edge_index (int32 or int64),
// writes converted src/edg and counts in one pass (saves a dispatch + re-read).
__global__ __launch_bounds__(256) void count_kernel(
    const int* __restrict__ raw, int* __restrict__ src, int* __restrict__ edg,
    int* __restrict__ cnt, int E, int nnz) {
  bool is64;
  {
    int l = threadIdx.x & 63;
    int v = raw[2 * l + 1];               // high words if int64 (values < 2^31)
    unsigned long long m = __ballot(v == 0);
    is64 = (m == ~0ull);
  }
  int g = blockIdx.x * 256 + threadIdx.x;
  if (g < nnz) {
    int s = is64 ? raw[2 * g] : raw[g];
    int e = is64 ? raw[2 * (nnz + g)] : raw[nnz + g];
    src[g] = s;
    edg[g] = e;
    atomicAdd(&cnt[e], 1);
    atomicAdd(&cnt[E + s], 1);
  }
}

// ---- 3-kernel exclusive scan of cnt[0..M) into P[0..M], P[M]=total ----
__global__ __launch_bounds__(256) void scanA_kernel(
    const int* __restrict__ cnt, int* __restrict__ P, int* __restrict__ BS, int M) {
  __shared__ int lds[256];
  int t = threadIdx.x;
  long base = blockIdx.x * 1024L;
  int v[4], ts = 0;
#pragma unroll
  for (int j = 0; j < 4; ++j) {
    long i = base + t * 4 + j;
    v[j] = (i < M) ? cnt[i] : 0;
    ts += v[j];
  }
  lds[t] = ts;
  __syncthreads();
  for (int off = 1; off < 256; off <<= 1) {
    int x = (t >= off) ? lds[t - off] : 0;
    __syncthreads();
    lds[t] += x;
    __syncthreads();
  }
  int run = lds[t] - ts;  // exclusive base for this thread
#pragma unroll
  for (int j = 0; j < 4; ++j) {
    long i = base + t * 4 + j;
    if (i < M) P[i] = run;
    run += v[j];
  }
  if (t == 255) BS[blockIdx.x] = lds[255];
}

__global__ void scanB_kernel(int* __restrict__ BS, int* __restrict__ P,
                             int nblocks, int M) {
  if (threadIdx.x == 0) {
    int run = 0;
    for (int i = 0; i < nblocks; ++i) { int x = BS[i]; BS[i] = run; run += x; }
    P[M] = run;
  }
}

__global__ __launch_bounds__(256) void scanC_kernel(
    int* __restrict__ P, const int* __restrict__ BS, int M) {
  long i = blockIdx.x * 256L + threadIdx.x;
  if (i < M) P[i] += BS[i >> 10];
}

// adj_e[P[e]..] = member nodes of edge e ; adj_n[P[E+i]-nnz..] = edges of node i
__global__ __launch_bounds__(256) void fill_adj_kernel(
    const int* __restrict__ src, const int* __restrict__ edg,
    const int* __restrict__ P, int* __restrict__ cnt,
    int* __restrict__ adj_e, int* __restrict__ adj_n, int E, int nnz) {
  int g = blockIdx.x * 256 + threadIdx.x;
  if (g < nnz) {
    int e = edg[g], s = src[g];
    int pe = P[e] + atomicAdd(&cnt[e], 1);
    adj_e[pe] = s;
    int pn = P[E + s] - nnz + atomicAdd(&cnt[E + s], 1);
    adj_n[pn] = e;
  }
}

// Wp = diag(a) @ W ; rvec = d @ W. The previous layer's BN affine (a,d) is
// computed INLINE from the running sums (folds finalize_bn away for layers
// 1,2): a = g*rsqrt(var+eps), d = beta - mu*a.
__global__ void prep_w_kernel(const float* __restrict__ W,
                              const float* __restrict__ sums,
                              const float* __restrict__ sumsq,
                              const float* __restrict__ gprev,
                              const float* __restrict__ betaprev,
                              float* __restrict__ Wp, float* __restrict__ rvec,
                              int has_aff, float inv_n) {
  __shared__ float sa[DIM], sd[DIM];
  int j = threadIdx.x;  // 0..127
  if (has_aff) {
    float mu = sums[j] * inv_n;
    float var = fmaf(sumsq[j], inv_n, -mu * mu);
    float a = gprev[j] * rsqrtf(var + 1e-5f);
    sa[j] = a;
    sd[j] = fmaf(-mu, a, betaprev[j]);
  } else {
    sa[j] = 1.0f;
    sd[j] = 0.0f;
  }
  __syncthreads();
  float racc = 0.0f;
  for (int c = 0; c < DIM; ++c) {
    float w = W[c * DIM + j];
    Wp[c * DIM + j] = sa[c] * w;
    racc = fmaf(sd[c], w, racc);
  }
  rvec[j] = racc;
}

// Layer-0 edge gather: reads fp32 node_attr DIRECTLY (512 B rows). By the
// measured row-rate invariant (~80cy/row regardless of width), this costs
// ~same as bf16 and deletes the cast_x pass entirely.
// Clamp-to-last loop + subtract-correction: pads duplicate row[kl] (L1-hot),
// then acc -= extra*row[kl]. No sentinel row, no per-load selects, OOB-safe.
__global__ __launch_bounds__(256) void edge_gather_f32_kernel(
    const float4* __restrict__ X4, const int* __restrict__ P,
    const int* __restrict__ adj_e, float* __restrict__ ag, int E) {
  int slot = threadIdx.x >> 5;
  int l = threadIdx.x & 31;
  int e = blockIdx.x * 8 + slot;
  if (e >= E) return;
  int p0 = P[e], p1 = P[e + 1];
  float4 a = {0.f, 0.f, 0.f, 0.f};
  int kl = p1 - 1;
  for (int k = p0; k < p1; k += 8) {
    int n0 = adj_e[min(k, kl)];
    int n1 = adj_e[min(k + 1, kl)];
    int n2 = adj_e[min(k + 2, kl)];
    int n3 = adj_e[min(k + 3, kl)];
    int n4 = adj_e[min(k + 4, kl)];
    int n5 = adj_e[min(k + 5, kl)];
    int n6 = adj_e[min(k + 6, kl)];
    int n7 = adj_e[min(k + 7, kl)];
    float4 q0 = X4[(size_t)n0 * 32 + l];
    float4 q1 = X4[(size_t)n1 * 32 + l];
    float4 q2 = X4[(size_t)n2 * 32 + l];
    float4 q3 = X4[(size_t)n3 * 32 + l];
    float4 q4 = X4[(size_t)n4 * 32 + l];
    float4 q5 = X4[(size_t)n5 * 32 + l];
    float4 q6 = X4[(size_t)n6 * 32 + l];
    float4 q7 = X4[(size_t)n7 * 32 + l];
    a.x += ((q0.x + q1.x) + (q2.x + q3.x)) + ((q4.x + q5.x) + (q6.x + q7.x));
    a.y += ((q0.y + q1.y) + (q2.y + q3.y)) + ((q4.y + q5.y) + (q6.y + q7.y));
    a.z += ((q0.z + q1.z) + (q2.z + q3.z)) + ((q4.z + q5.z) + (q6.z + q7.z));
    a.w += ((q0.w + q1.w) + (q2.w + q3.w)) + ((q4.w + q5.w) + (q6.w + q7.w));
  }
  int deg = p1 - p0;
  if (deg > 0) {
    int extra = ((deg + 7) & ~7) - deg;
    if (extra) {
      float4 ql = X4[(size_t)adj_e[kl] * 32 + l];
      float ex = (float)extra;
      a.x -= ex * ql.x; a.y -= ex * ql.y; a.z -= ex * ql.z; a.w -= ex * ql.w;
    }
  }
  float binv = (deg > 0) ? 1.0f / (float)deg : 0.0f;
  f32x4 o;
  o.x = a.x * binv; o.y = a.y * binv; o.z = a.z * binv; o.w = a.w * binv;
  __builtin_nontemporal_store(o, &((f32x4*)ag)[(size_t)e * 32 + l]);
}

// Layers 1,2: gather bf16 z rows (256 B). Same clamp-to-last + correction.
__global__ __launch_bounds__(256) void edge_gather_bf16_kernel(
    const uint2* __restrict__ xh, const int* __restrict__ P,
    const int* __restrict__ adj_e, float* __restrict__ ag, int E) {
  int slot = threadIdx.x >> 5;
  int l = threadIdx.x & 31;
  int e = blockIdx.x * 8 + slot;
  if (e >= E) return;
  int p0 = P[e], p1 = P[e + 1];
  float4 a = {0.f, 0.f, 0.f, 0.f};
  int kl = p1 - 1;
  for (int k = p0; k < p1; k += 8) {
    int n0 = adj_e[min(k, kl)];
    int n1 = adj_e[min(k + 1, kl)];
    int n2 = adj_e[min(k + 2, kl)];
    int n3 = adj_e[min(k + 3, kl)];
    int n4 = adj_e[min(k + 4, kl)];
    int n5 = adj_e[min(k + 5, kl)];
    int n6 = adj_e[min(k + 6, kl)];
    int n7 = adj_e[min(k + 7, kl)];
    uint2 q0 = xh[(size_t)n0 * 32 + l];
    uint2 q1 = xh[(size_t)n1 * 32 + l];
    uint2 q2 = xh[(size_t)n2 * 32 + l];
    uint2 q3 = xh[(size_t)n3 * 32 + l];
    uint2 q4 = xh[(size_t)n4 * 32 + l];
    uint2 q5 = xh[(size_t)n5 * 32 + l];
    uint2 q6 = xh[(size_t)n6 * 32 + l];
    uint2 q7 = xh[(size_t)n7 * 32 + l];
    a.x += ((bf_lo(q0.x) + bf_lo(q1.x)) + (bf_lo(q2.x) + bf_lo(q3.x))) +
           ((bf_lo(q4.x) + bf_lo(q5.x)) + (bf_lo(q6.x) + bf_lo(q7.x)));
    a.y += ((bf_hi(q0.x) + bf_hi(q1.x)) + (bf_hi(q2.x) + bf_hi(q3.x))) +
           ((bf_hi(q4.x) + bf_hi(q5.x)) + (bf_hi(q6.x) + bf_hi(q7.x)));
    a.z += ((bf_lo(q0.y) + bf_lo(q1.y)) + (bf_lo(q2.y) + bf_lo(q3.y))) +
           ((bf_lo(q4.y) + bf_lo(q5.y)) + (bf_lo(q6.y) + bf_lo(q7.y)));
    a.w += ((bf_hi(q0.y) + bf_hi(q1.y)) + (bf_hi(q2.y) + bf_hi(q3.y))) +
           ((bf_hi(q4.y) + bf_hi(q5.y)) + (bf_hi(q6.y) + bf_hi(q7.y)));
  }
  int deg = p1 - p0;
  if (deg > 0) {
    int extra = ((deg + 7) & ~7) - deg;
    if (extra) {
      uint2 ql = xh[(size_t)adj_e[kl] * 32 + l];
      float ex = (float)extra;
      a.x -= ex * bf_lo(ql.x); a.y -= ex * bf_hi(ql.x);
      a.z -= ex * bf_lo(ql.y); a.w -= ex * bf_hi(ql.y);
    }
  }
  float binv = (deg > 0) ? 1.0f / (float)deg : 0.0f;
  f32x4 o;
  o.x = a.x * binv; o.y = a.y * binv; o.z = a.z * binv; o.w = a.w * binv;
  __builtin_nontemporal_store(o, &((f32x4*)ag)[(size_t)e * 32 + l]);
}

// efh[E x 128 bf16] = (ag @ Wp + rvec), zeroed for empty edges (deg==0).
// fp32 accumulate, bf16 pack on store. Normal stores (seed L2/L3 for
// node_gather).
__global__ __launch_bounds__(256) void gemm128_kernel(
    const float* __restrict__ X, const float* __restrict__ Wp,
    const float* __restrict__ rvec, const int* __restrict__ Pdeg,
    unsigned* __restrict__ Yh, int nrows) {
  __shared__ float sW[32 * DIM];   // sW[kk*128 + j]
  __shared__ float sX[DIM * 36];   // sX[rr*36 + kk], 36 keeps 16B align + pad
  const int t = threadIdx.x;
  const int row0 = blockIdx.x * DIM;
  const int tx = t & 15, ty = t >> 4;
  const int col0 = tx * 8, lr0 = ty * 8;
  float acc[8][8];
#pragma unroll
  for (int i = 0; i < 8; ++i)
#pragma unroll
    for (int j = 0; j < 8; ++j) acc[i][j] = 0.0f;

  for (int kc = 0; kc < 4; ++kc) {
    __syncthreads();
    {
      const float4* W4 = (const float4*)(Wp + kc * 32 * DIM);
      float4* sW4 = (float4*)sW;
#pragma unroll
      for (int i = 0; i < 4; ++i) sW4[t + i * 256] = W4[t + i * 256];
    }
#pragma unroll
    for (int i = 0; i < 4; ++i) {
      int q = t + i * 256;            // 0..1023 float4 slots
      int rr = q >> 3, kq = q & 7;
      int gr = row0 + rr; if (gr >= nrows) gr = nrows - 1;  // stores are guarded
      float4 v = *(const float4*)&X[(size_t)gr * DIM + kc * 32 + kq * 4];
      *(float4*)&sX[rr * 36 + kq * 4] = v;
    }
    __syncthreads();
    for (int kk = 0; kk < 32; ++kk) {
      float4 w0 = *(const float4*)&sW[kk * DIM + col0];
      float4 w1 = *(const float4*)&sW[kk * DIM + col0 + 4];
      float wv[8] = {w0.x, w0.y, w0.z, w0.w, w1.x, w1.y, w1.z, w1.w};
      float xv[8];
#pragma unroll
      for (int i = 0; i < 8; ++i) xv[i] = sX[(lr0 + i) * 36 + kk];
#pragma unroll
      for (int i = 0; i < 8; ++i)
#pragma unroll
        for (int j = 0; j < 8; ++j) acc[i][j] = fmaf(xv[i], wv[j], acc[i][j]);
    }
  }
  float4 r0 = *(const float4*)&rvec[col0];
  float4 r1 = *(const float4*)&rvec[col0 + 4];
#pragma unroll
  for (int i = 0; i < 8; ++i) {
    int gr = row0 + lr0 + i;
    if (gr < nrows) {
      // empty segment must produce 0 (reference: Binv=0 ⇒ e_feat=0),
      // not rvec — guard with the degree.
      float nz = (Pdeg[gr + 1] > Pdeg[gr]) ? 1.0f : 0.0f;
      float o0x = (acc[i][0] + r0.x) * nz, o0y = (acc[i][1] + r0.y) * nz;
      float o0z = (acc[i][2] + r0.z) * nz, o0w = (acc[i][3] + r0.w) * nz;
      float o1x = (acc[i][4] + r1.x) * nz, o1y = (acc[i][5] + r1.y) * nz;
      float o1z = (acc[i][6] + r1.z) * nz, o1w = (acc[i][7] + r1.w) * nz;
      uint4 st;
      st.x = pk_bf16(o0x, o0y);
      st.y = pk_bf16(o0z, o0w);
      st.z = pk_bf16(o1x, o1y);
      st.w = pk_bf16(o1z, o1w);
      *(uint4*)&Yh[(size_t)gr * 64 + (col0 >> 1)] = st;
    }
  }
}

// zh[i][c] = bf16(relu(Dinv_i * sum_{e ni i} ef[e][c] + b_c)), fused BN stats.
// Exact grid (cdiv(N,8) blocks), no grid-stride. Clamp-to-last + correction.
__global__ __launch_bounds__(256) void node_gather_kernel(
    const uint2* __restrict__ ef, const int* __restrict__ P,
    const int* __restrict__ adj_n, const float* __restrict__ b,
    uint2* __restrict__ zh, float* __restrict__ sum,
    float* __restrict__ sumsq, int E, int N, int nnz) {
  __shared__ float lsum[DIM], lsumsq[DIM];
  int t = threadIdx.x;
  if (t < DIM) { lsum[t] = 0.f; lsumsq[t] = 0.f; }
  __syncthreads();
  int slot = t >> 5;
  int l = t & 31;
  float4 s1 = {0.f, 0.f, 0.f, 0.f}, s2 = {0.f, 0.f, 0.f, 0.f};
  int i = blockIdx.x * 8 + slot;
  if (i < N) {
    float4 bc = ((const float4*)b)[l];
    int p0 = P[E + i] - nnz, p1 = P[E + i + 1] - nnz;
    float4 a = {0.f, 0.f, 0.f, 0.f};
    int kl = p1 - 1;
    for (int k = p0; k < p1; k += 8) {
      int e0 = adj_n[min(k, kl)];
      int e1 = adj_n[min(k + 1, kl)];
      int e2 = adj_n[min(k + 2, kl)];
      int e3 = adj_n[min(k + 3, kl)];
      int e4 = adj_n[min(k + 4, kl)];
      int e5 = adj_n[min(k + 5, kl)];
      int e6 = adj_n[min(k + 6, kl)];
      int e7 = adj_n[min(k + 7, kl)];
      uint2 q0 = ef[(size_t)e0 * 32 + l];
      uint2 q1 = ef[(size_t)e1 * 32 + l];
      uint2 q2 = ef[(size_t)e2 * 32 + l];
      uint2 q3 = ef[(size_t)e3 * 32 + l];
      uint2 q4 = ef[(size_t)e4 * 32 + l];
      uint2 q5 = ef[(size_t)e5 * 32 + l];
      uint2 q6 = ef[(size_t)e6 * 32 + l];
      uint2 q7 = ef[(size_t)e7 * 32 + l];
      a.x += ((bf_lo(q0.x) + bf_lo(q1.x)) + (bf_lo(q2.x) + bf_lo(q3.x))) +
             ((bf_lo(q4.x) + bf_lo(q5.x)) + (bf_lo(q6.x) + bf_lo(q7.x)));
      a.y += ((bf_hi(q0.x) + bf_hi(q1.x)) + (bf_hi(q2.x) + bf_hi(q3.x))) +
             ((bf_hi(q4.x) + bf_hi(q5.x)) + (bf_hi(q6.x) + bf_hi(q7.x)));
      a.z += ((bf_lo(q0.y) + bf_lo(q1.y)) + (bf_lo(q2.y) + bf_lo(q3.y))) +
             ((bf_lo(q4.y) + bf_lo(q5.y)) + (bf_lo(q6.y) + bf_lo(q7.y)));
      a.w += ((bf_hi(q0.y) + bf_hi(q1.y)) + (bf_hi(q2.y) + bf_hi(q3.y))) +
             ((bf_hi(q4.y) + bf_hi(q5.y)) + (bf_hi(q6.y) + bf_hi(q7.y)));
    }
    int deg = p1 - p0;
    if (deg > 0) {
      int extra = ((deg + 7) & ~7) - deg;
      if (extra) {
        uint2 ql = ef[(size_t)adj_n[kl] * 32 + l];
        float ex = (float)extra;
        a.x -= ex * bf_lo(ql.x); a.y -= ex * bf_hi(ql.x);
        a.z -= ex * bf_lo(ql.y); a.w -= ex * bf_hi(ql.y);
      }
    }
    float dinv = (deg > 0) ? 1.0f / (float)deg : 0.0f;
    float4 v;
    v.x = fmaxf(fmaf(dinv, a.x, bc.x), 0.f);
    v.y = fmaxf(fmaf(dinv, a.y, bc.y), 0.f);
    v.z = fmaxf(fmaf(dinv, a.z, bc.z), 0.f);
    v.w = fmaxf(fmaf(dinv, a.w, bc.w), 0.f);
    uint2 o;
    o.x = pk_bf16(v.x, v.y);
    o.y = pk_bf16(v.z, v.w);
    zh[(size_t)i * 32 + l] = o;
    s1.x += v.x; s1.y += v.y; s1.z += v.z; s1.w += v.w;
    s2.x = fmaf(v.x, v.x, s2.x); s2.y = fmaf(v.y, v.y, s2.y);
    s2.z = fmaf(v.z, v.z, s2.z); s2.w = fmaf(v.w, v.w, s2.w);
  }
  int c0 = l * 4;
  atomicAdd(&lsum[c0 + 0], s1.x); atomicAdd(&lsum[c0 + 1], s1.y);
  atomicAdd(&lsum[c0 + 2], s1.z); atomicAdd(&lsum[c0 + 3], s1.w);
  atomicAdd(&lsumsq[c0 + 0], s2.x); atomicAdd(&lsumsq[c0 + 1], s2.y);
  atomicAdd(&lsumsq[c0 + 2], s2.z); atomicAdd(&lsumsq[c0 + 3], s2.w);
  __syncthreads();
  if (t < DIM) {
    atomicAdd(&sum[t], lsum[t]);
    atomicAdd(&sumsq[t], lsumsq[t]);
  }
}

// aff_a = g*rsqrt(var+eps); aff_d = beta - mu*aff_a  (layer 2 only)
__global__ void finalize_bn_kernel(const float* __restrict__ sum,
                                   const float* __restrict__ sumsq,
                                   const float* __restrict__ g,
                                   const float* __restrict__ beta,
                                   float* __restrict__ aff_a, float* __restrict__ aff_d,
                                   int n) {
  int c = threadIdx.x;
  float inv_n = 1.0f / (float)n;
  float mu = sum[c] * inv_n;
  float var = fmaf(sumsq[c], inv_n, -mu * mu);
  float a = g[c] * rsqrtf(var + 1e-5f);
  aff_a[c] = a;
  aff_d[c] = fmaf(-mu, a, beta[c]);
}

// out = aff_a*zh + aff_d (bf16 zh -> fp32 out, nt store: final output only)
__global__ __launch_bounds__(256) void apply_affine_kernel(
    const uint2* __restrict__ zh, const float* __restrict__ aff_a,
    const float* __restrict__ aff_d, float* __restrict__ out, long total4) {
  long i = blockIdx.x * 256L + threadIdx.x;
  if (i >= total4) return;
  int c4 = (int)(i & 31);
  float4 a = ((const float4*)aff_a)[c4];
  float4 d = ((const float4*)aff_d)[c4];
  uint2 q = zh[i];
  f32x4 o;
  o.x = fmaf(a.x, bf_lo(q.x), d.x);
  o.y = fmaf(a.y, bf_hi(q.x), d.y);
  o.z = fmaf(a.z, bf_lo(q.y), d.z);
  o.w = fmaf(a.w, bf_hi(q.y), d.w);
  __builtin_nontemporal_store(o, &((f32x4*)out)[i]);
}

extern "C" void kernel_launch(void* const* d_in, const int* in_sizes, int n_in,
                              void* d_out, int out_size, void* d_ws, size_t ws_size,
                              hipStream_t stream) {
  const int NNZv = in_sizes[0] / 2;
  const int Nv   = in_sizes[1] / DIM;
  const int Ev   = in_sizes[2] / DIM;
  const int* eidx_raw = (const int*)d_in[0];
  const float* node_attr = (const float*)d_in[1];

  // ---- workspace layout (~47 MB total) ----
  float* bufE  = (float*)d_ws;                 // E*128 f32 (ag)
  float* Wp    = bufE + (size_t)Ev * DIM;      // 128*128
  float* rvec  = Wp + DIM * DIM;               // 128
  float* sums  = rvec + 128;                   // 128
  float* sumsq = sums + 128;                   // 128
  float* aff_a = sumsq + 128;                  // 128
  float* aff_d = aff_a + 128;                  // 128
  // src/edg/cnt dead after fill_adj -> reused as efh: (E+1)*64 uints
  // = 5.12 MB <= src+edg+cnt region (5.28 MB).
  int* src   = (int*)(aff_d + 128);            // NNZ
  int* edg   = src + NNZv;                     // NNZ
  int* cnt   = edg + NNZv;                     // E+N (padded to x4)
  int* P     = cnt + (((size_t)Ev + Nv + 3) & ~(size_t)3);  // E+N+1 (padded)
  int* BS    = P + (((size_t)Ev + Nv + 1 + 3) & ~(size_t)3); // <=256 block sums
  int* adj_e = BS + 256;                       // NNZ
  int* adj_n = adj_e + NNZv;                   // NNZ
  unsigned* efh = (unsigned*)src;              // (E+1)*64 uints (bf16 ef rows)
  uint2* xh = (uint2*)(adj_n + NNZv);          // (N+1)*32 uint2 (bf16 z)

  const int M = Ev + Nv;
  const int nbA = cdiv(M, 1024);
  const float inv_n = 1.0f / (float)Nv;

  hipMemsetAsync(cnt, 0, (size_t)M * 4, stream);
  count_kernel<<<cdiv(NNZv, 256), 256, 0, stream>>>(eidx_raw, src, edg, cnt, Ev, NNZv);
  scanA_kernel<<<nbA, 256, 0, stream>>>(cnt, P, BS, M);
  scanB_kernel<<<1, 64, 0, stream>>>(BS, P, nbA, M);
  scanC_kernel<<<cdiv(M, 256), 256, 0, stream>>>(P, BS, M);
  hipMemsetAsync(cnt, 0, (size_t)M * 4, stream);
  fill_adj_kernel<<<cdiv(NNZv, 256), 256, 0, stream>>>(src, edg, P, cnt, adj_e, adj_n, Ev, NNZv);

  for (int l = 0; l < 3; ++l) {
    const float* W     = (const float*)d_in[3 + l * 4];
    const float* b     = (const float*)d_in[4 + l * 4];
    // previous layer's BN params (folded into this layer's GEMM)
    const float* gprev    = (const float*)d_in[5 + (l > 0 ? l - 1 : 0) * 4];
    const float* betaprev = (const float*)d_in[6 + (l > 0 ? l - 1 : 0) * 4];

    prep_w_kernel<<<1, 128, 0, stream>>>(W, sums, sumsq, gprev, betaprev,
                                         Wp, rvec, l > 0 ? 1 : 0, inv_n);
    if (l == 0)
      edge_gather_f32_kernel<<<cdiv(Ev, 8), 256, 0, stream>>>(
          (const float4*)node_attr, P, adj_e, bufE, Ev);
    else
      edge_gather_bf16_kernel<<<cdiv(Ev, 8), 256, 0, stream>>>(
          xh, P, adj_e, bufE, Ev);
    gemm128_kernel<<<cdiv(Ev, DIM), 256, 0, stream>>>(bufE, Wp, rvec, P, efh, Ev);
    hipMemsetAsync(sums, 0, 256 * 4, stream);
    node_gather_kernel<<<cdiv(Nv, 8), 256, 0, stream>>>(
        (const uint2*)efh, P, adj_n, b, xh, sums, sumsq, Ev, Nv, NNZv);
  }
  {
    const float* g2    = (const float*)d_in[5 + 2 * 4];
    const float* beta2 = (const float*)d_in[6 + 2 * 4];
    finalize_bn_kernel<<<1, 128, 0, stream>>>(sums, sumsq, g2, beta2, aff_a, aff_d, Nv);
  }
  apply_affine_kernel<<<cdiv((long)Nv * 32, 256), 256, 0, stream>>>(
      xh, aff_a, aff_d, (float*)d_out, (long)Nv * 32);
}

// Round 8
// 714.425 us; speedup vs baseline: 2.0767x; 2.0767x over previous
//
#include <hip/hip_runtime.h>
#include <stdint.h>

#define DIM 128

static inline int cdiv(long a, long b) { return (int)((a + b - 1) / b); }

// clang ext-vector types: __builtin_nontemporal_* requires real vector types.
typedef float f32x4 __attribute__((ext_vector_type(4)));

// ---- bf16 pack/unpack (RNE) ----
__device__ __forceinline__ unsigned pk_bf16(float a, float b) {
  unsigned ua = __float_as_uint(a), ub = __float_as_uint(b);
  ua = (ua + 0x7FFFu + ((ua >> 16) & 1u)) >> 16;
  ub = (ub + 0x7FFFu + ((ub >> 16) & 1u)) >> 16;
  return ua | (ub << 16);
}
__device__ __forceinline__ float bf_lo(unsigned u) { return __uint_as_float(u << 16); }
__device__ __forceinline__ float bf_hi(unsigned u) { return __uint_as_float(u & 0xFFFF0000u); }

// Merged index-convert + degree-count: reads raw edge_index (int32 or int64),
// writes converted src/edg and counts in one pass (saves a dispatch + re-read).
__global__ __launch_bounds__(256) void count_kernel(
    const int* __restrict__ raw, int* __restrict__ src, int* __restrict__ edg,
    int* __restrict__ cnt, int E, int nnz) {
  bool is64;
  {
    int l = threadIdx.x & 63;
    int v = raw[2 * l + 1];               // high words if int64 (values < 2^31)
    unsigned long long m = __ballot(v == 0);
    is64 = (m == ~0ull);
  }
  int g = blockIdx.x * 256 + threadIdx.x;
  if (g < nnz) {
    int s = is64 ? raw[2 * g] : raw[g];
    int e = is64 ? raw[2 * (nnz + g)] : raw[nnz + g];
    src[g] = s;
    edg[g] = e;
    atomicAdd(&cnt[e], 1);
    atomicAdd(&cnt[E + s], 1);
  }
}

// ---- 3-kernel exclusive scan of cnt[0..M) into P[0..M], P[M]=total ----
__global__ __launch_bounds__(256) void scanA_kernel(
    const int* __restrict__ cnt, int* __restrict__ P, int* __restrict__ BS, int M) {
  __shared__ int lds[256];
  int t = threadIdx.x;
  long base = blockIdx.x * 1024L;
  int v[4], ts = 0;
#pragma unroll
  for (int j = 0; j < 4; ++j) {
    long i = base + t * 4 + j;
    v[j] = (i < M) ? cnt[i] : 0;
    ts += v[j];
  }
  lds[t] = ts;
  __syncthreads();
  for (int off = 1; off < 256; off <<= 1) {
    int x = (t >= off) ? lds[t - off] : 0;
    __syncthreads();
    lds[t] += x;
    __syncthreads();
  }
  int run = lds[t] - ts;  // exclusive base for this thread
#pragma unroll
  for (int j = 0; j < 4; ++j) {
    long i = base + t * 4 + j;
    if (i < M) P[i] = run;
    run += v[j];
  }
  if (t == 255) BS[blockIdx.x] = lds[255];
}

__global__ void scanB_kernel(int* __restrict__ BS, int* __restrict__ P,
                             int nblocks, int M) {
  if (threadIdx.x == 0) {
    int run = 0;
    for (int i = 0; i < nblocks; ++i) { int x = BS[i]; BS[i] = run; run += x; }
    P[M] = run;
  }
}

__global__ __launch_bounds__(256) void scanC_kernel(
    int* __restrict__ P, const int* __restrict__ BS, int M) {
  long i = blockIdx.x * 256L + threadIdx.x;
  if (i < M) P[i] += BS[i >> 10];
}

// adj_e[P[e]..] = member nodes of edge e ; adj_n[P[E+i]-nnz..] = edges of node i
__global__ __launch_bounds__(256) void fill_adj_kernel(
    const int* __restrict__ src, const int* __restrict__ edg,
    const int* __restrict__ P, int* __restrict__ cnt,
    int* __restrict__ adj_e, int* __restrict__ adj_n, int E, int nnz) {
  int g = blockIdx.x * 256 + threadIdx.x;
  if (g < nnz) {
    int e = edg[g], s = src[g];
    int pe = P[e] + atomicAdd(&cnt[e], 1);
    adj_e[pe] = s;
    int pn = P[E + s] - nnz + atomicAdd(&cnt[E + s], 1);
    adj_n[pn] = e;
  }
}

// Wp = diag(a) @ W ; rvec = d @ W. The previous layer's BN affine (a,d) is
// computed INLINE from the running sums (folds finalize_bn away for layers
// 1,2): a = g*rsqrt(var+eps), d = beta - mu*a.
__global__ void prep_w_kernel(const float* __restrict__ W,
                              const float* __restrict__ sums,
                              const float* __restrict__ sumsq,
                              const float* __restrict__ gprev,
                              const float* __restrict__ betaprev,
                              float* __restrict__ Wp, float* __restrict__ rvec,
                              int has_aff, float inv_n) {
  __shared__ float sa[DIM], sd[DIM];
  int j = threadIdx.x;  // 0..127
  if (has_aff) {
    float mu = sums[j] * inv_n;
    float var = fmaf(sumsq[j], inv_n, -mu * mu);
    float a = gprev[j] * rsqrtf(var + 1e-5f);
    sa[j] = a;
    sd[j] = fmaf(-mu, a, betaprev[j]);
  } else {
    sa[j] = 1.0f;
    sd[j] = 0.0f;
  }
  __syncthreads();
  float racc = 0.0f;
  for (int c = 0; c < DIM; ++c) {
    float w = W[c * DIM + j];
    Wp[c * DIM + j] = sa[c] * w;
    racc = fmaf(sd[c], w, racc);
  }
  rvec[j] = racc;
}

// Layer-0 edge gather: reads fp32 node_attr DIRECTLY (512 B rows), deleting
// the cast_x pass (row-rate invariant: ~80cy/row regardless of width).
// Clamp-to-last loop + subtract-correction: pads duplicate row[kl] (L1-hot),
// then acc -= extra*row[kl]. No sentinel row, no per-load selects, OOB-safe.
__global__ __launch_bounds__(256) void edge_gather_f32_kernel(
    const float4* __restrict__ X4, const int* __restrict__ P,
    const int* __restrict__ adj_e, float* __restrict__ ag, int E) {
  int slot = threadIdx.x >> 5;
  int l = threadIdx.x & 31;
  int e = blockIdx.x * 8 + slot;
  if (e >= E) return;
  int p0 = P[e], p1 = P[e + 1];
  float4 a = {0.f, 0.f, 0.f, 0.f};
  int kl = p1 - 1;
  for (int k = p0; k < p1; k += 8) {
    int n0 = adj_e[min(k, kl)];
    int n1 = adj_e[min(k + 1, kl)];
    int n2 = adj_e[min(k + 2, kl)];
    int n3 = adj_e[min(k + 3, kl)];
    int n4 = adj_e[min(k + 4, kl)];
    int n5 = adj_e[min(k + 5, kl)];
    int n6 = adj_e[min(k + 6, kl)];
    int n7 = adj_e[min(k + 7, kl)];
    float4 q0 = X4[(size_t)n0 * 32 + l];
    float4 q1 = X4[(size_t)n1 * 32 + l];
    float4 q2 = X4[(size_t)n2 * 32 + l];
    float4 q3 = X4[(size_t)n3 * 32 + l];
    float4 q4 = X4[(size_t)n4 * 32 + l];
    float4 q5 = X4[(size_t)n5 * 32 + l];
    float4 q6 = X4[(size_t)n6 * 32 + l];
    float4 q7 = X4[(size_t)n7 * 32 + l];
    a.x += ((q0.x + q1.x) + (q2.x + q3.x)) + ((q4.x + q5.x) + (q6.x + q7.x));
    a.y += ((q0.y + q1.y) + (q2.y + q3.y)) + ((q4.y + q5.y) + (q6.y + q7.y));
    a.z += ((q0.z + q1.z) + (q2.z + q3.z)) + ((q4.z + q5.z) + (q6.z + q7.z));
    a.w += ((q0.w + q1.w) + (q2.w + q3.w)) + ((q4.w + q5.w) + (q6.w + q7.w));
  }
  int deg = p1 - p0;
  if (deg > 0) {
    int extra = ((deg + 7) & ~7) - deg;
    if (extra) {
      float4 ql = X4[(size_t)adj_e[kl] * 32 + l];
      float ex = (float)extra;
      a.x -= ex * ql.x; a.y -= ex * ql.y; a.z -= ex * ql.z; a.w -= ex * ql.w;
    }
  }
  float binv = (deg > 0) ? 1.0f / (float)deg : 0.0f;
  f32x4 o;
  o.x = a.x * binv; o.y = a.y * binv; o.z = a.z * binv; o.w = a.w * binv;
  __builtin_nontemporal_store(o, &((f32x4*)ag)[(size_t)e * 32 + l]);
}

// Layers 1,2: gather bf16 z rows (256 B). Same clamp-to-last + correction.
__global__ __launch_bounds__(256) void edge_gather_bf16_kernel(
    const uint2* __restrict__ xh, const int* __restrict__ P,
    const int* __restrict__ adj_e, float* __restrict__ ag, int E) {
  int slot = threadIdx.x >> 5;
  int l = threadIdx.x & 31;
  int e = blockIdx.x * 8 + slot;
  if (e >= E) return;
  int p0 = P[e], p1 = P[e + 1];
  float4 a = {0.f, 0.f, 0.f, 0.f};
  int kl = p1 - 1;
  for (int k = p0; k < p1; k += 8) {
    int n0 = adj_e[min(k, kl)];
    int n1 = adj_e[min(k + 1, kl)];
    int n2 = adj_e[min(k + 2, kl)];
    int n3 = adj_e[min(k + 3, kl)];
    int n4 = adj_e[min(k + 4, kl)];
    int n5 = adj_e[min(k + 5, kl)];
    int n6 = adj_e[min(k + 6, kl)];
    int n7 = adj_e[min(k + 7, kl)];
    uint2 q0 = xh[(size_t)n0 * 32 + l];
    uint2 q1 = xh[(size_t)n1 * 32 + l];
    uint2 q2 = xh[(size_t)n2 * 32 + l];
    uint2 q3 = xh[(size_t)n3 * 32 + l];
    uint2 q4 = xh[(size_t)n4 * 32 + l];
    uint2 q5 = xh[(size_t)n5 * 32 + l];
    uint2 q6 = xh[(size_t)n6 * 32 + l];
    uint2 q7 = xh[(size_t)n7 * 32 + l];
    a.x += ((bf_lo(q0.x) + bf_lo(q1.x)) + (bf_lo(q2.x) + bf_lo(q3.x))) +
           ((bf_lo(q4.x) + bf_lo(q5.x)) + (bf_lo(q6.x) + bf_lo(q7.x)));
    a.y += ((bf_hi(q0.x) + bf_hi(q1.x)) + (bf_hi(q2.x) + bf_hi(q3.x))) +
           ((bf_hi(q4.x) + bf_hi(q5.x)) + (bf_hi(q6.x) + bf_hi(q7.x)));
    a.z += ((bf_lo(q0.y) + bf_lo(q1.y)) + (bf_lo(q2.y) + bf_lo(q3.y))) +
           ((bf_lo(q4.y) + bf_lo(q5.y)) + (bf_lo(q6.y) + bf_lo(q7.y)));
    a.w += ((bf_hi(q0.y) + bf_hi(q1.y)) + (bf_hi(q2.y) + bf_hi(q3.y))) +
           ((bf_hi(q4.y) + bf_hi(q5.y)) + (bf_hi(q6.y) + bf_hi(q7.y)));
  }
  int deg = p1 - p0;
  if (deg > 0) {
    int extra = ((deg + 7) & ~7) - deg;
    if (extra) {
      uint2 ql = xh[(size_t)adj_e[kl] * 32 + l];
      float ex = (float)extra;
      a.x -= ex * bf_lo(ql.x); a.y -= ex * bf_hi(ql.x);
      a.z -= ex * bf_lo(ql.y); a.w -= ex * bf_hi(ql.y);
    }
  }
  float binv = (deg > 0) ? 1.0f / (float)deg : 0.0f;
  f32x4 o;
  o.x = a.x * binv; o.y = a.y * binv; o.z = a.z * binv; o.w = a.w * binv;
  __builtin_nontemporal_store(o, &((f32x4*)ag)[(size_t)e * 32 + l]);
}

// efh[E x 128 bf16] = (ag @ Wp + rvec), zeroed for empty edges (deg==0).
// fp32 accumulate, bf16 pack on store. Normal stores (seed L2/L3 for
// node_gather).
__global__ __launch_bounds__(256) void gemm128_kernel(
    const float* __restrict__ X, const float* __restrict__ Wp,
    const float* __restrict__ rvec, const int* __restrict__ Pdeg,
    unsigned* __restrict__ Yh, int nrows) {
  __shared__ float sW[32 * DIM];   // sW[kk*128 + j]
  __shared__ float sX[DIM * 36];   // sX[rr*36 + kk], 36 keeps 16B align + pad
  const int t = threadIdx.x;
  const int row0 = blockIdx.x * DIM;
  const int tx = t & 15, ty = t >> 4;
  const int col0 = tx * 8, lr0 = ty * 8;
  float acc[8][8];
#pragma unroll
  for (int i = 0; i < 8; ++i)
#pragma unroll
    for (int j = 0; j < 8; ++j) acc[i][j] = 0.0f;

  for (int kc = 0; kc < 4; ++kc) {
    __syncthreads();
    {
      const float4* W4 = (const float4*)(Wp + kc * 32 * DIM);
      float4* sW4 = (float4*)sW;
#pragma unroll
      for (int i = 0; i < 4; ++i) sW4[t + i * 256] = W4[t + i * 256];
    }
#pragma unroll
    for (int i = 0; i < 4; ++i) {
      int q = t + i * 256;            // 0..1023 float4 slots
      int rr = q >> 3, kq = q & 7;
      int gr = row0 + rr; if (gr >= nrows) gr = nrows - 1;  // stores are guarded
      float4 v = *(const float4*)&X[(size_t)gr * DIM + kc * 32 + kq * 4];
      *(float4*)&sX[rr * 36 + kq * 4] = v;
    }
    __syncthreads();
    for (int kk = 0; kk < 32; ++kk) {
      float4 w0 = *(const float4*)&sW[kk * DIM + col0];
      float4 w1 = *(const float4*)&sW[kk * DIM + col0 + 4];
      float wv[8] = {w0.x, w0.y, w0.z, w0.w, w1.x, w1.y, w1.z, w1.w};
      float xv[8];
#pragma unroll
      for (int i = 0; i < 8; ++i) xv[i] = sX[(lr0 + i) * 36 + kk];
#pragma unroll
      for (int i = 0; i < 8; ++i)
#pragma unroll
        for (int j = 0; j < 8; ++j) acc[i][j] = fmaf(xv[i], wv[j], acc[i][j]);
    }
  }
  float4 r0 = *(const float4*)&rvec[col0];
  float4 r1 = *(const float4*)&rvec[col0 + 4];
#pragma unroll
  for (int i = 0; i < 8; ++i) {
    int gr = row0 + lr0 + i;
    if (gr < nrows) {
      // empty segment must produce 0 (reference: Binv=0 ⇒ e_feat=0),
      // not rvec — guard with the degree.
      float nz = (Pdeg[gr + 1] > Pdeg[gr]) ? 1.0f : 0.0f;
      float o0x = (acc[i][0] + r0.x) * nz, o0y = (acc[i][1] + r0.y) * nz;
      float o0z = (acc[i][2] + r0.z) * nz, o0w = (acc[i][3] + r0.w) * nz;
      float o1x = (acc[i][4] + r1.x) * nz, o1y = (acc[i][5] + r1.y) * nz;
      float o1z = (acc[i][6] + r1.z) * nz, o1w = (acc[i][7] + r1.w) * nz;
      uint4 st;
      st.x = pk_bf16(o0x, o0y);
      st.y = pk_bf16(o0z, o0w);
      st.z = pk_bf16(o1x, o1y);
      st.w = pk_bf16(o1z, o1w);
      *(uint4*)&Yh[(size_t)gr * 64 + (col0 >> 1)] = st;
    }
  }
}

// zh[i][c] = bf16(relu(Dinv_i * sum_{e ni i} ef[e][c] + b_c)), fused BN stats.
// GRID-STRIDE at 2048 blocks (R7 lesson: the per-block BN fan-in costs 256
// global atomics to 16 cache lines — at 12500 blocks that serialization alone
// was ~260us. Block count must stay small). Clamp-to-last + correction loop.
__global__ __launch_bounds__(256) void node_gather_kernel(
    const uint2* __restrict__ ef, const int* __restrict__ P,
    const int* __restrict__ adj_n, const float* __restrict__ b,
    uint2* __restrict__ zh, float* __restrict__ sum,
    float* __restrict__ sumsq, int E, int N, int nnz) {
  __shared__ float lsum[DIM], lsumsq[DIM];
  int t = threadIdx.x;
  if (t < DIM) { lsum[t] = 0.f; lsumsq[t] = 0.f; }
  __syncthreads();
  int slot = t >> 5;
  int l = t & 31;
  float4 bc = ((const float4*)b)[l];
  float4 s1 = {0.f, 0.f, 0.f, 0.f}, s2 = {0.f, 0.f, 0.f, 0.f};
  for (int i = blockIdx.x * 8 + slot; i < N; i += gridDim.x * 8) {
    int p0 = P[E + i] - nnz, p1 = P[E + i + 1] - nnz;
    float4 a = {0.f, 0.f, 0.f, 0.f};
    int kl = p1 - 1;
    for (int k = p0; k < p1; k += 8) {
      int e0 = adj_n[min(k, kl)];
      int e1 = adj_n[min(k + 1, kl)];
      int e2 = adj_n[min(k + 2, kl)];
      int e3 = adj_n[min(k + 3, kl)];
      int e4 = adj_n[min(k + 4, kl)];
      int e5 = adj_n[min(k + 5, kl)];
      int e6 = adj_n[min(k + 6, kl)];
      int e7 = adj_n[min(k + 7, kl)];
      uint2 q0 = ef[(size_t)e0 * 32 + l];
      uint2 q1 = ef[(size_t)e1 * 32 + l];
      uint2 q2 = ef[(size_t)e2 * 32 + l];
      uint2 q3 = ef[(size_t)e3 * 32 + l];
      uint2 q4 = ef[(size_t)e4 * 32 + l];
      uint2 q5 = ef[(size_t)e5 * 32 + l];
      uint2 q6 = ef[(size_t)e6 * 32 + l];
      uint2 q7 = ef[(size_t)e7 * 32 + l];
      a.x += ((bf_lo(q0.x) + bf_lo(q1.x)) + (bf_lo(q2.x) + bf_lo(q3.x))) +
             ((bf_lo(q4.x) + bf_lo(q5.x)) + (bf_lo(q6.x) + bf_lo(q7.x)));
      a.y += ((bf_hi(q0.x) + bf_hi(q1.x)) + (bf_hi(q2.x) + bf_hi(q3.x))) +
             ((bf_hi(q4.x) + bf_hi(q5.x)) + (bf_hi(q6.x) + bf_hi(q7.x)));
      a.z += ((bf_lo(q0.y) + bf_lo(q1.y)) + (bf_lo(q2.y) + bf_lo(q3.y))) +
             ((bf_lo(q4.y) + bf_lo(q5.y)) + (bf_lo(q6.y) + bf_lo(q7.y)));
      a.w += ((bf_hi(q0.y) + bf_hi(q1.y)) + (bf_hi(q2.y) + bf_hi(q3.y))) +
             ((bf_hi(q4.y) + bf_hi(q5.y)) + (bf_hi(q6.y) + bf_hi(q7.y)));
    }
    int deg = p1 - p0;
    if (deg > 0) {
      int extra = ((deg + 7) & ~7) - deg;
      if (extra) {
        uint2 ql = ef[(size_t)adj_n[kl] * 32 + l];
        float ex = (float)extra;
        a.x -= ex * bf_lo(ql.x); a.y -= ex * bf_hi(ql.x);
        a.z -= ex * bf_lo(ql.y); a.w -= ex * bf_hi(ql.y);
      }
    }
    float dinv = (deg > 0) ? 1.0f / (float)deg : 0.0f;
    float4 v;
    v.x = fmaxf(fmaf(dinv, a.x, bc.x), 0.f);
    v.y = fmaxf(fmaf(dinv, a.y, bc.y), 0.f);
    v.z = fmaxf(fmaf(dinv, a.z, bc.z), 0.f);
    v.w = fmaxf(fmaf(dinv, a.w, bc.w), 0.f);
    uint2 o;
    o.x = pk_bf16(v.x, v.y);
    o.y = pk_bf16(v.z, v.w);
    zh[(size_t)i * 32 + l] = o;
    s1.x += v.x; s1.y += v.y; s1.z += v.z; s1.w += v.w;
    s2.x = fmaf(v.x, v.x, s2.x); s2.y = fmaf(v.y, v.y, s2.y);
    s2.z = fmaf(v.z, v.z, s2.z); s2.w = fmaf(v.w, v.w, s2.w);
  }
  int c0 = l * 4;
  atomicAdd(&lsum[c0 + 0], s1.x); atomicAdd(&lsum[c0 + 1], s1.y);
  atomicAdd(&lsum[c0 + 2], s1.z); atomicAdd(&lsum[c0 + 3], s1.w);
  atomicAdd(&lsumsq[c0 + 0], s2.x); atomicAdd(&lsumsq[c0 + 1], s2.y);
  atomicAdd(&lsumsq[c0 + 2], s2.z); atomicAdd(&lsumsq[c0 + 3], s2.w);
  __syncthreads();
  if (t < DIM) {
    atomicAdd(&sum[t], lsum[t]);
    atomicAdd(&sumsq[t], lsumsq[t]);
  }
}

// aff_a = g*rsqrt(var+eps); aff_d = beta - mu*aff_a  (layer 2 only)
__global__ void finalize_bn_kernel(const float* __restrict__ sum,
                                   const float* __restrict__ sumsq,
                                   const float* __restrict__ g,
                                   const float* __restrict__ beta,
                                   float* __restrict__ aff_a, float* __restrict__ aff_d,
                                   int n) {
  int c = threadIdx.x;
  float inv_n = 1.0f / (float)n;
  float mu = sum[c] * inv_n;
  float var = fmaf(sumsq[c], inv_n, -mu * mu);
  float a = g[c] * rsqrtf(var + 1e-5f);
  aff_a[c] = a;
  aff_d[c] = fmaf(-mu, a, beta[c]);
}

// out = aff_a*zh + aff_d (bf16 zh -> fp32 out, nt store: final output only)
__global__ __launch_bounds__(256) void apply_affine_kernel(
    const uint2* __restrict__ zh, const float* __restrict__ aff_a,
    const float* __restrict__ aff_d, float* __restrict__ out, long total4) {
  long i = blockIdx.x * 256L + threadIdx.x;
  if (i >= total4) return;
  int c4 = (int)(i & 31);
  float4 a = ((const float4*)aff_a)[c4];
  float4 d = ((const float4*)aff_d)[c4];
  uint2 q = zh[i];
  f32x4 o;
  o.x = fmaf(a.x, bf_lo(q.x), d.x);
  o.y = fmaf(a.y, bf_hi(q.x), d.y);
  o.z = fmaf(a.z, bf_lo(q.y), d.z);
  o.w = fmaf(a.w, bf_hi(q.y), d.w);
  __builtin_nontemporal_store(o, &((f32x4*)out)[i]);
}

extern "C" void kernel_launch(void* const* d_in, const int* in_sizes, int n_in,
                              void* d_out, int out_size, void* d_ws, size_t ws_size,
                              hipStream_t stream) {
  const int NNZv = in_sizes[0] / 2;
  const int Nv   = in_sizes[1] / DIM;
  const int Ev   = in_sizes[2] / DIM;
  const int* eidx_raw = (const int*)d_in[0];
  const float* node_attr = (const float*)d_in[1];

  // ---- workspace layout (~47 MB total) ----
  float* bufE  = (float*)d_ws;                 // E*128 f32 (ag)
  float* Wp    = bufE + (size_t)Ev * DIM;      // 128*128
  float* rvec  = Wp + DIM * DIM;               // 128
  float* sums  = rvec + 128;                   // 128
  float* sumsq = sums + 128;                   // 128
  float* aff_a = sumsq + 128;                  // 128
  float* aff_d = aff_a + 128;                  // 128
  // src/edg/cnt dead after fill_adj -> reused as efh: (E+1)*64 uints
  // = 5.12 MB <= src+edg+cnt region (5.28 MB).
  int* src   = (int*)(aff_d + 128);            // NNZ
  int* edg   = src + NNZv;                     // NNZ
  int* cnt   = edg + NNZv;                     // E+N (padded to x4)
  int* P     = cnt + (((size_t)Ev + Nv + 3) & ~(size_t)3);  // E+N+1 (padded)
  int* BS    = P + (((size_t)Ev + Nv + 1 + 3) & ~(size_t)3); // <=256 block sums
  int* adj_e = BS + 256;                       // NNZ
  int* adj_n = adj_e + NNZv;                   // NNZ
  unsigned* efh = (unsigned*)src;              // (E+1)*64 uints (bf16 ef rows)
  uint2* xh = (uint2*)(adj_n + NNZv);          // (N+1)*32 uint2 (bf16 z)

  const int M = Ev + Nv;
  const int nbA = cdiv(M, 1024);
  const float inv_n = 1.0f / (float)Nv;

  hipMemsetAsync(cnt, 0, (size_t)M * 4, stream);
  count_kernel<<<cdiv(NNZv, 256), 256, 0, stream>>>(eidx_raw, src, edg, cnt, Ev, NNZv);
  scanA_kernel<<<nbA, 256, 0, stream>>>(cnt, P, BS, M);
  scanB_kernel<<<1, 64, 0, stream>>>(BS, P, nbA, M);
  scanC_kernel<<<cdiv(M, 256), 256, 0, stream>>>(P, BS, M);
  hipMemsetAsync(cnt, 0, (size_t)M * 4, stream);
  fill_adj_kernel<<<cdiv(NNZv, 256), 256, 0, stream>>>(src, edg, P, cnt, adj_e, adj_n, Ev, NNZv);

  for (int l = 0; l < 3; ++l) {
    const float* W     = (const float*)d_in[3 + l * 4];
    const float* b     = (const float*)d_in[4 + l * 4];
    // previous layer's BN params (folded into this layer's GEMM)
    const float* gprev    = (const float*)d_in[5 + (l > 0 ? l - 1 : 0) * 4];
    const float* betaprev = (const float*)d_in[6 + (l > 0 ? l - 1 : 0) * 4];

    prep_w_kernel<<<1, 128, 0, stream>>>(W, sums, sumsq, gprev, betaprev,
                                         Wp, rvec, l > 0 ? 1 : 0, inv_n);
    if (l == 0)
      edge_gather_f32_kernel<<<cdiv(Ev, 8), 256, 0, stream>>>(
          (const float4*)node_attr, P, adj_e, bufE, Ev);
    else
      edge_gather_bf16_kernel<<<cdiv(Ev, 8), 256, 0, stream>>>(
          xh, P, adj_e, bufE, Ev);
    gemm128_kernel<<<cdiv(Ev, DIM), 256, 0, stream>>>(bufE, Wp, rvec, P, efh, Ev);
    hipMemsetAsync(sums, 0, 256 * 4, stream);
    node_gather_kernel<<<2048, 256, 0, stream>>>(
        (const uint2*)efh, P, adj_n, b, xh, sums, sumsq, Ev, Nv, NNZv);
  }
  {
    const float* g2    = (const float*)d_in[5 + 2 * 4];
    const float* beta2 = (const float*)d_in[6 + 2 * 4];
    finalize_bn_kernel<<<1, 128, 0, stream>>>(sums, sumsq, g2, beta2, aff_a, aff_d, Nv);
  }
  apply_affine_kernel<<<cdiv((long)Nv * 32, 256), 256, 0, stream>>>(
      xh, aff_a, aff_d, (float*)d_out, (long)Nv * 32);
}

// Round 9
// 702.862 us; speedup vs baseline: 2.1108x; 1.0165x over previous
//
#include <hip/hip_runtime.h>
#include <stdint.h>

#define DIM 128

static inline int cdiv(long a, long b) { return (int)((a + b - 1) / b); }

// clang ext-vector types: __builtin_nontemporal_* requires real vector types.
typedef float f32x4 __attribute__((ext_vector_type(4)));

// ---- bf16 pack/unpack (RNE) ----
__device__ __forceinline__ unsigned pk_bf16(float a, float b) {
  unsigned ua = __float_as_uint(a), ub = __float_as_uint(b);
  ua = (ua + 0x7FFFu + ((ua >> 16) & 1u)) >> 16;
  ub = (ub + 0x7FFFu + ((ub >> 16) & 1u)) >> 16;
  return ua | (ub << 16);
}
__device__ __forceinline__ float bf_lo(unsigned u) { return __uint_as_float(u << 16); }
__device__ __forceinline__ float bf_hi(unsigned u) { return __uint_as_float(u & 0xFFFF0000u); }

__device__ __forceinline__ void acc8(float4& a, const uint2* q) {
  a.x += ((bf_lo(q[0].x) + bf_lo(q[1].x)) + (bf_lo(q[2].x) + bf_lo(q[3].x))) +
         ((bf_lo(q[4].x) + bf_lo(q[5].x)) + (bf_lo(q[6].x) + bf_lo(q[7].x)));
  a.y += ((bf_hi(q[0].x) + bf_hi(q[1].x)) + (bf_hi(q[2].x) + bf_hi(q[3].x))) +
         ((bf_hi(q[4].x) + bf_hi(q[5].x)) + (bf_hi(q[6].x) + bf_hi(q[7].x)));
  a.z += ((bf_lo(q[0].y) + bf_lo(q[1].y)) + (bf_lo(q[2].y) + bf_lo(q[3].y))) +
         ((bf_lo(q[4].y) + bf_lo(q[5].y)) + (bf_lo(q[6].y) + bf_lo(q[7].y)));
  a.w += ((bf_hi(q[0].y) + bf_hi(q[1].y)) + (bf_hi(q[2].y) + bf_hi(q[3].y))) +
         ((bf_hi(q[4].y) + bf_hi(q[5].y)) + (bf_hi(q[6].y) + bf_hi(q[7].y)));
}

// Merged index-convert + degree-count.
__global__ __launch_bounds__(256) void count_kernel(
    const int* __restrict__ raw, int* __restrict__ src, int* __restrict__ edg,
    int* __restrict__ cnt, int E, int nnz) {
  bool is64;
  {
    int l = threadIdx.x & 63;
    int v = raw[2 * l + 1];               // high words if int64 (values < 2^31)
    unsigned long long m = __ballot(v == 0);
    is64 = (m == ~0ull);
  }
  int g = blockIdx.x * 256 + threadIdx.x;
  if (g < nnz) {
    int s = is64 ? raw[2 * g] : raw[g];
    int e = is64 ? raw[2 * (nnz + g)] : raw[nnz + g];
    src[g] = s;
    edg[g] = e;
    atomicAdd(&cnt[e], 1);
    atomicAdd(&cnt[E + s], 1);
  }
}

// ---- 3-kernel exclusive scan of cnt[0..M) into P[0..M], P[M]=total ----
__global__ __launch_bounds__(256) void scanA_kernel(
    const int* __restrict__ cnt, int* __restrict__ P, int* __restrict__ BS, int M) {
  __shared__ int lds[256];
  int t = threadIdx.x;
  long base = blockIdx.x * 1024L;
  int v[4], ts = 0;
#pragma unroll
  for (int j = 0; j < 4; ++j) {
    long i = base + t * 4 + j;
    v[j] = (i < M) ? cnt[i] : 0;
    ts += v[j];
  }
  lds[t] = ts;
  __syncthreads();
  for (int off = 1; off < 256; off <<= 1) {
    int x = (t >= off) ? lds[t - off] : 0;
    __syncthreads();
    lds[t] += x;
    __syncthreads();
  }
  int run = lds[t] - ts;  // exclusive base for this thread
#pragma unroll
  for (int j = 0; j < 4; ++j) {
    long i = base + t * 4 + j;
    if (i < M) P[i] = run;
    run += v[j];
  }
  if (t == 255) BS[blockIdx.x] = lds[255];
}

__global__ void scanB_kernel(int* __restrict__ BS, int* __restrict__ P,
                             int nblocks, int M) {
  if (threadIdx.x == 0) {
    int run = 0;
    for (int i = 0; i < nblocks; ++i) { int x = BS[i]; BS[i] = run; run += x; }
    P[M] = run;
  }
}

__global__ __launch_bounds__(256) void scanC_kernel(
    int* __restrict__ P, const int* __restrict__ BS, int M) {
  long i = blockIdx.x * 256L + threadIdx.x;
  if (i < M) P[i] += BS[i >> 10];
}

// adj_e[P[e]..] = member nodes of edge e ; adj_n[P[E+i]-nnz..] = edges of node i
__global__ __launch_bounds__(256) void fill_adj_kernel(
    const int* __restrict__ src, const int* __restrict__ edg,
    const int* __restrict__ P, int* __restrict__ cnt,
    int* __restrict__ adj_e, int* __restrict__ adj_n, int E, int nnz) {
  int g = blockIdx.x * 256 + threadIdx.x;
  if (g < nnz) {
    int e = edg[g], s = src[g];
    int pe = P[e] + atomicAdd(&cnt[e], 1);
    adj_e[pe] = s;
    int pn = P[E + s] - nnz + atomicAdd(&cnt[E + s], 1);
    adj_n[pn] = e;
  }
}

// PARALLEL prep_w (R8 lesson: the 1-block version serially reads 64 KB on one
// CU ~= 10-15us/layer). 8 blocks x 256 threads; block b owns c in
// [b*16,b*16+16), thread (j=t&127, half=t>>7) handles 8 c's. BN affine of the
// previous layer computed inline from running sums. rvec accumulated via LDS
// reduce + 128 atomicAdd/block into pre-zeroed rvec.
__global__ __launch_bounds__(256) void prep_w_kernel(
    const float* __restrict__ W, const float* __restrict__ sums,
    const float* __restrict__ sumsq, const float* __restrict__ gprev,
    const float* __restrict__ betaprev, float* __restrict__ Wp,
    float* __restrict__ rvec, int has_aff, float inv_n) {
  __shared__ float red[256];
  int t = threadIdx.x;
  int j = t & 127;
  int half = t >> 7;
  int c0 = blockIdx.x * 16 + half * 8;
  float racc = 0.f;
#pragma unroll
  for (int cc = 0; cc < 8; ++cc) {
    int c = c0 + cc;
    float a = 1.0f, d = 0.0f;
    if (has_aff) {
      float mu = sums[c] * inv_n;
      float var = fmaf(sumsq[c], inv_n, -mu * mu);
      a = gprev[c] * rsqrtf(var + 1e-5f);
      d = fmaf(-mu, a, betaprev[c]);
    }
    float w = W[c * DIM + j];
    Wp[c * DIM + j] = a * w;
    racc = fmaf(d, w, racc);
  }
  red[t] = racc;
  __syncthreads();
  if (t < 128) atomicAdd(&rvec[j], red[t] + red[t + 128]);
}

// Layer-0 edge gather: fp32 node_attr directly (512 B rows), 8-chunk
// clamp-to-last + subtract-correction.
__global__ __launch_bounds__(256) void edge_gather_f32_kernel(
    const float4* __restrict__ X4, const int* __restrict__ P,
    const int* __restrict__ adj_e, float* __restrict__ ag, int E) {
  int slot = threadIdx.x >> 5;
  int l = threadIdx.x & 31;
  int e = blockIdx.x * 8 + slot;
  if (e >= E) return;
  int p0 = P[e], p1 = P[e + 1];
  float4 a = {0.f, 0.f, 0.f, 0.f};
  int kl = p1 - 1;
  for (int k = p0; k < p1; k += 8) {
    int n0 = adj_e[min(k, kl)];
    int n1 = adj_e[min(k + 1, kl)];
    int n2 = adj_e[min(k + 2, kl)];
    int n3 = adj_e[min(k + 3, kl)];
    int n4 = adj_e[min(k + 4, kl)];
    int n5 = adj_e[min(k + 5, kl)];
    int n6 = adj_e[min(k + 6, kl)];
    int n7 = adj_e[min(k + 7, kl)];
    float4 q0 = X4[(size_t)n0 * 32 + l];
    float4 q1 = X4[(size_t)n1 * 32 + l];
    float4 q2 = X4[(size_t)n2 * 32 + l];
    float4 q3 = X4[(size_t)n3 * 32 + l];
    float4 q4 = X4[(size_t)n4 * 32 + l];
    float4 q5 = X4[(size_t)n5 * 32 + l];
    float4 q6 = X4[(size_t)n6 * 32 + l];
    float4 q7 = X4[(size_t)n7 * 32 + l];
    a.x += ((q0.x + q1.x) + (q2.x + q3.x)) + ((q4.x + q5.x) + (q6.x + q7.x));
    a.y += ((q0.y + q1.y) + (q2.y + q3.y)) + ((q4.y + q5.y) + (q6.y + q7.y));
    a.z += ((q0.z + q1.z) + (q2.z + q3.z)) + ((q4.z + q5.z) + (q6.z + q7.z));
    a.w += ((q0.w + q1.w) + (q2.w + q3.w)) + ((q4.w + q5.w) + (q6.w + q7.w));
  }
  int deg = p1 - p0;
  if (deg > 0) {
    int extra = ((deg + 7) & ~7) - deg;
    if (extra) {
      float4 ql = X4[(size_t)adj_e[kl] * 32 + l];
      float ex = (float)extra;
      a.x -= ex * ql.x; a.y -= ex * ql.y; a.z -= ex * ql.z; a.w -= ex * ql.w;
    }
  }
  float binv = (deg > 0) ? 1.0f / (float)deg : 0.0f;
  f32x4 o;
  o.x = a.x * binv; o.y = a.y * binv; o.z = a.z * binv; o.w = a.w * binv;
  __builtin_nontemporal_store(o, &((f32x4*)ag)[(size_t)e * 32 + l]);
}

// Layers 1,2: gather bf16 z rows. Mean edge size = NNZ/E = 30 -> the 8-chunk
// loop ran ~4 SERIALIZED rounds per edge (each chunk's ef loads wait behind
// the previous chunk's accumulate-waitcnt). 16-wide chunk halves the rounds:
// 16 independent row loads in flight per lane.
__global__ __launch_bounds__(256) void edge_gather_bf16_kernel(
    const uint2* __restrict__ xh, const int* __restrict__ P,
    const int* __restrict__ adj_e, float* __restrict__ ag, int E) {
  int slot = threadIdx.x >> 5;
  int l = threadIdx.x & 31;
  int e = blockIdx.x * 8 + slot;
  if (e >= E) return;
  int p0 = P[e], p1 = P[e + 1];
  float4 a = {0.f, 0.f, 0.f, 0.f};
  int kl = p1 - 1;
  for (int k = p0; k < p1; k += 16) {
    int n[16];
#pragma unroll
    for (int j = 0; j < 16; ++j) n[j] = adj_e[min(k + j, kl)];
    uint2 q[16];
#pragma unroll
    for (int j = 0; j < 16; ++j) q[j] = xh[(size_t)n[j] * 32 + l];
    acc8(a, q);
    acc8(a, q + 8);
  }
  int deg = p1 - p0;
  if (deg > 0) {
    int extra = ((deg + 15) & ~15) - deg;
    if (extra) {
      uint2 ql = xh[(size_t)adj_e[kl] * 32 + l];
      float ex = (float)extra;
      a.x -= ex * bf_lo(ql.x); a.y -= ex * bf_hi(ql.x);
      a.z -= ex * bf_lo(ql.y); a.w -= ex * bf_hi(ql.y);
    }
  }
  float binv = (deg > 0) ? 1.0f / (float)deg : 0.0f;
  f32x4 o;
  o.x = a.x * binv; o.y = a.y * binv; o.z = a.z * binv; o.w = a.w * binv;
  __builtin_nontemporal_store(o, &((f32x4*)ag)[(size_t)e * 32 + l]);
}

// efh[E x 128 bf16] = (ag @ Wp + rvec), zeroed for empty edges (deg==0).
__global__ __launch_bounds__(256) void gemm128_kernel(
    const float* __restrict__ X, const float* __restrict__ Wp,
    const float* __restrict__ rvec, const int* __restrict__ Pdeg,
    unsigned* __restrict__ Yh, int nrows) {
  __shared__ float sW[32 * DIM];   // sW[kk*128 + j]
  __shared__ float sX[DIM * 36];   // sX[rr*36 + kk], 36 keeps 16B align + pad
  const int t = threadIdx.x;
  const int row0 = blockIdx.x * DIM;
  const int tx = t & 15, ty = t >> 4;
  const int col0 = tx * 8, lr0 = ty * 8;
  float acc[8][8];
#pragma unroll
  for (int i = 0; i < 8; ++i)
#pragma unroll
    for (int j = 0; j < 8; ++j) acc[i][j] = 0.0f;

  for (int kc = 0; kc < 4; ++kc) {
    __syncthreads();
    {
      const float4* W4 = (const float4*)(Wp + kc * 32 * DIM);
      float4* sW4 = (float4*)sW;
#pragma unroll
      for (int i = 0; i < 4; ++i) sW4[t + i * 256] = W4[t + i * 256];
    }
#pragma unroll
    for (int i = 0; i < 4; ++i) {
      int q = t + i * 256;            // 0..1023 float4 slots
      int rr = q >> 3, kq = q & 7;
      int gr = row0 + rr; if (gr >= nrows) gr = nrows - 1;  // stores are guarded
      float4 v = *(const float4*)&X[(size_t)gr * DIM + kc * 32 + kq * 4];
      *(float4*)&sX[rr * 36 + kq * 4] = v;
    }
    __syncthreads();
    for (int kk = 0; kk < 32; ++kk) {
      float4 w0 = *(const float4*)&sW[kk * DIM + col0];
      float4 w1 = *(const float4*)&sW[kk * DIM + col0 + 4];
      float wv[8] = {w0.x, w0.y, w0.z, w0.w, w1.x, w1.y, w1.z, w1.w};
      float xv[8];
#pragma unroll
      for (int i = 0; i < 8; ++i) xv[i] = sX[(lr0 + i) * 36 + kk];
#pragma unroll
      for (int i = 0; i < 8; ++i)
#pragma unroll
        for (int j = 0; j < 8; ++j) acc[i][j] = fmaf(xv[i], wv[j], acc[i][j]);
    }
  }
  float4 r0 = *(const float4*)&rvec[col0];
  float4 r1 = *(const float4*)&rvec[col0 + 4];
#pragma unroll
  for (int i = 0; i < 8; ++i) {
    int gr = row0 + lr0 + i;
    if (gr < nrows) {
      // empty segment must produce 0 (reference: Binv=0 ⇒ e_feat=0).
      float nz = (Pdeg[gr + 1] > Pdeg[gr]) ? 1.0f : 0.0f;
      float o0x = (acc[i][0] + r0.x) * nz, o0y = (acc[i][1] + r0.y) * nz;
      float o0z = (acc[i][2] + r0.z) * nz, o0w = (acc[i][3] + r0.w) * nz;
      float o1x = (acc[i][4] + r1.x) * nz, o1y = (acc[i][5] + r1.y) * nz;
      float o1z = (acc[i][6] + r1.z) * nz, o1w = (acc[i][7] + r1.w) * nz;
      uint4 st;
      st.x = pk_bf16(o0x, o0y);
      st.y = pk_bf16(o0z, o0w);
      st.z = pk_bf16(o1x, o1y);
      st.w = pk_bf16(o1z, o1w);
      *(uint4*)&Yh[(size_t)gr * 64 + (col0 >> 1)] = st;
    }
  }
}

// zh[i][c] = bf16(relu(Dinv_i * sum_{e ni i} ef[e][c] + b_c)), fused BN stats.
// 2048 blocks grid-stride (R7: BN atomic fan-in scales with gridDim).
// TWO-NODE INTERLEAVE: each slot processes nodes i and i+G concurrently —
// two independent P->adj->ef chains, 16 ef loads in flight, attacking the
// ~900cy serial chain per node (deg~6 = single chunk).
__global__ __launch_bounds__(256) void node_gather_kernel(
    const uint2* __restrict__ ef, const int* __restrict__ P,
    const int* __restrict__ adj_n, const float* __restrict__ b,
    uint2* __restrict__ zh, float* __restrict__ sum,
    float* __restrict__ sumsq, int E, int N, int nnz) {
  __shared__ float lsum[DIM], lsumsq[DIM];
  int t = threadIdx.x;
  if (t < DIM) { lsum[t] = 0.f; lsumsq[t] = 0.f; }
  __syncthreads();
  int slot = t >> 5;
  int l = t & 31;
  float4 bc = ((const float4*)b)[l];
  float4 s1 = {0.f, 0.f, 0.f, 0.f}, s2 = {0.f, 0.f, 0.f, 0.f};
  const int G = gridDim.x * 8;
  for (int i = blockIdx.x * 8 + slot; i < N; i += 2 * G) {
    int iB = i + G;
    bool hasB = iB < N;
    int pA0 = P[E + i] - nnz, pA1 = P[E + i + 1] - nnz;
    int pB0 = 0, pB1 = 0;
    if (hasB) { pB0 = P[E + iB] - nnz; pB1 = P[E + iB + 1] - nnz; }
    float4 aA = {0.f, 0.f, 0.f, 0.f}, aB = {0.f, 0.f, 0.f, 0.f};
    int klA = pA1 - 1, klB = pB1 - 1;
    int kA = pA0, kB = pB0;
    while ((kA < pA1) || (kB < pB1)) {
      bool dA = kA < pA1, dB = kB < pB1;
      int eA[8], eB[8];
      if (dA) {
#pragma unroll
        for (int j = 0; j < 8; ++j) eA[j] = adj_n[min(kA + j, klA)];
      }
      if (dB) {
#pragma unroll
        for (int j = 0; j < 8; ++j) eB[j] = adj_n[min(kB + j, klB)];
      }
      uint2 qA[8], qB[8];
      if (dA) {
#pragma unroll
        for (int j = 0; j < 8; ++j) qA[j] = ef[(size_t)eA[j] * 32 + l];
      }
      if (dB) {
#pragma unroll
        for (int j = 0; j < 8; ++j) qB[j] = ef[(size_t)eB[j] * 32 + l];
      }
      if (dA) { acc8(aA, qA); kA += 8; }
      if (dB) { acc8(aB, qB); kB += 8; }
    }
    // corrections + epilogue A
    {
      int deg = pA1 - pA0;
      if (deg > 0) {
        int extra = ((deg + 7) & ~7) - deg;
        if (extra) {
          uint2 ql = ef[(size_t)adj_n[klA] * 32 + l];
          float ex = (float)extra;
          aA.x -= ex * bf_lo(ql.x); aA.y -= ex * bf_hi(ql.x);
          aA.z -= ex * bf_lo(ql.y); aA.w -= ex * bf_hi(ql.y);
        }
      }
      float dinv = (deg > 0) ? 1.0f / (float)deg : 0.0f;
      float4 v;
      v.x = fmaxf(fmaf(dinv, aA.x, bc.x), 0.f);
      v.y = fmaxf(fmaf(dinv, aA.y, bc.y), 0.f);
      v.z = fmaxf(fmaf(dinv, aA.z, bc.z), 0.f);
      v.w = fmaxf(fmaf(dinv, aA.w, bc.w), 0.f);
      uint2 o;
      o.x = pk_bf16(v.x, v.y);
      o.y = pk_bf16(v.z, v.w);
      zh[(size_t)i * 32 + l] = o;
      s1.x += v.x; s1.y += v.y; s1.z += v.z; s1.w += v.w;
      s2.x = fmaf(v.x, v.x, s2.x); s2.y = fmaf(v.y, v.y, s2.y);
      s2.z = fmaf(v.z, v.z, s2.z); s2.w = fmaf(v.w, v.w, s2.w);
    }
    // corrections + epilogue B
    if (hasB) {
      int deg = pB1 - pB0;
      if (deg > 0) {
        int extra = ((deg + 7) & ~7) - deg;
        if (extra) {
          uint2 ql = ef[(size_t)adj_n[klB] * 32 + l];
          float ex = (float)extra;
          aB.x -= ex * bf_lo(ql.x); aB.y -= ex * bf_hi(ql.x);
          aB.z -= ex * bf_lo(ql.y); aB.w -= ex * bf_hi(ql.y);
        }
      }
      float dinv = (deg > 0) ? 1.0f / (float)deg : 0.0f;
      float4 v;
      v.x = fmaxf(fmaf(dinv, aB.x, bc.x), 0.f);
      v.y = fmaxf(fmaf(dinv, aB.y, bc.y), 0.f);
      v.z = fmaxf(fmaf(dinv, aB.z, bc.z), 0.f);
      v.w = fmaxf(fmaf(dinv, aB.w, bc.w), 0.f);
      uint2 o;
      o.x = pk_bf16(v.x, v.y);
      o.y = pk_bf16(v.z, v.w);
      zh[(size_t)iB * 32 + l] = o;
      s1.x += v.x; s1.y += v.y; s1.z += v.z; s1.w += v.w;
      s2.x = fmaf(v.x, v.x, s2.x); s2.y = fmaf(v.y, v.y, s2.y);
      s2.z = fmaf(v.z, v.z, s2.z); s2.w = fmaf(v.w, v.w, s2.w);
    }
  }
  int c0 = l * 4;
  atomicAdd(&lsum[c0 + 0], s1.x); atomicAdd(&lsum[c0 + 1], s1.y);
  atomicAdd(&lsum[c0 + 2], s1.z); atomicAdd(&lsum[c0 + 3], s1.w);
  atomicAdd(&lsumsq[c0 + 0], s2.x); atomicAdd(&lsumsq[c0 + 1], s2.y);
  atomicAdd(&lsumsq[c0 + 2], s2.z); atomicAdd(&lsumsq[c0 + 3], s2.w);
  __syncthreads();
  if (t < DIM) {
    atomicAdd(&sum[t], lsum[t]);
    atomicAdd(&sumsq[t], lsumsq[t]);
  }
}

// aff_a = g*rsqrt(var+eps); aff_d = beta - mu*aff_a  (layer 2 only)
__global__ void finalize_bn_kernel(const float* __restrict__ sum,
                                   const float* __restrict__ sumsq,
                                   const float* __restrict__ g,
                                   const float* __restrict__ beta,
                                   float* __restrict__ aff_a, float* __restrict__ aff_d,
                                   int n) {
  int c = threadIdx.x;
  float inv_n = 1.0f / (float)n;
  float mu = sum[c] * inv_n;
  float var = fmaf(sumsq[c], inv_n, -mu * mu);
  float a = g[c] * rsqrtf(var + 1e-5f);
  aff_a[c] = a;
  aff_d[c] = fmaf(-mu, a, beta[c]);
}

// out = aff_a*zh + aff_d (bf16 zh -> fp32 out, nt store: final output only)
__global__ __launch_bounds__(256) void apply_affine_kernel(
    const uint2* __restrict__ zh, const float* __restrict__ aff_a,
    const float* __restrict__ aff_d, float* __restrict__ out, long total4) {
  long i = blockIdx.x * 256L + threadIdx.x;
  if (i >= total4) return;
  int c4 = (int)(i & 31);
  float4 a = ((const float4*)aff_a)[c4];
  float4 d = ((const float4*)aff_d)[c4];
  uint2 q = zh[i];
  f32x4 o;
  o.x = fmaf(a.x, bf_lo(q.x), d.x);
  o.y = fmaf(a.y, bf_hi(q.x), d.y);
  o.z = fmaf(a.z, bf_lo(q.y), d.z);
  o.w = fmaf(a.w, bf_hi(q.y), d.w);
  __builtin_nontemporal_store(o, &((f32x4*)out)[i]);
}

extern "C" void kernel_launch(void* const* d_in, const int* in_sizes, int n_in,
                              void* d_out, int out_size, void* d_ws, size_t ws_size,
                              hipStream_t stream) {
  const int NNZv = in_sizes[0] / 2;
  const int Nv   = in_sizes[1] / DIM;
  const int Ev   = in_sizes[2] / DIM;
  const int* eidx_raw = (const int*)d_in[0];
  const float* node_attr = (const float*)d_in[1];

  // ---- workspace layout (~47 MB total) ----
  float* bufE  = (float*)d_ws;                 // E*128 f32 (ag)
  float* Wp    = bufE + (size_t)Ev * DIM;      // 128*128
  float* rvec  = Wp + DIM * DIM;               // 128
  float* sums  = rvec + 128;                   // 128
  float* sumsq = sums + 128;                   // 128
  float* aff_a = sumsq + 128;                  // 128
  float* aff_d = aff_a + 128;                  // 128
  int* src   = (int*)(aff_d + 128);            // NNZ
  int* edg   = src + NNZv;                     // NNZ
  int* cnt   = edg + NNZv;                     // E+N (padded to x4)
  int* P     = cnt + (((size_t)Ev + Nv + 3) & ~(size_t)3);  // E+N+1 (padded)
  int* BS    = P + (((size_t)Ev + Nv + 1 + 3) & ~(size_t)3); // <=256 block sums
  int* adj_e = BS + 256;                       // NNZ
  int* adj_n = adj_e + NNZv;                   // NNZ
  unsigned* efh = (unsigned*)src;              // (E+1)*64 uints (bf16 ef rows)
  uint2* xh = (uint2*)(adj_n + NNZv);          // (N+1)*32 uint2 (bf16 z)

  const int M = Ev + Nv;
  const int nbA = cdiv(M, 1024);
  const float inv_n = 1.0f / (float)Nv;

  hipMemsetAsync(cnt, 0, (size_t)M * 4, stream);
  count_kernel<<<cdiv(NNZv, 256), 256, 0, stream>>>(eidx_raw, src, edg, cnt, Ev, NNZv);
  scanA_kernel<<<nbA, 256, 0, stream>>>(cnt, P, BS, M);
  scanB_kernel<<<1, 64, 0, stream>>>(BS, P, nbA, M);
  scanC_kernel<<<cdiv(M, 256), 256, 0, stream>>>(P, BS, M);
  hipMemsetAsync(cnt, 0, (size_t)M * 4, stream);
  fill_adj_kernel<<<cdiv(NNZv, 256), 256, 0, stream>>>(src, edg, P, cnt, adj_e, adj_n, Ev, NNZv);

  for (int l = 0; l < 3; ++l) {
    const float* W     = (const float*)d_in[3 + l * 4];
    const float* b     = (const float*)d_in[4 + l * 4];
    const float* gprev    = (const float*)d_in[5 + (l > 0 ? l - 1 : 0) * 4];
    const float* betaprev = (const float*)d_in[6 + (l > 0 ? l - 1 : 0) * 4];

    hipMemsetAsync(rvec, 0, 128 * 4, stream);
    prep_w_kernel<<<8, 256, 0, stream>>>(W, sums, sumsq, gprev, betaprev,
                                         Wp, rvec, l > 0 ? 1 : 0, inv_n);
    if (l == 0)
      edge_gather_f32_kernel<<<cdiv(Ev, 8), 256, 0, stream>>>(
          (const float4*)node_attr, P, adj_e, bufE, Ev);
    else
      edge_gather_bf16_kernel<<<cdiv(Ev, 8), 256, 0, stream>>>(
          xh, P, adj_e, bufE, Ev);
    gemm128_kernel<<<cdiv(Ev, DIM), 256, 0, stream>>>(bufE, Wp, rvec, P, efh, Ev);
    hipMemsetAsync(sums, 0, 256 * 4, stream);
    node_gather_kernel<<<2048, 256, 0, stream>>>(
        (const uint2*)efh, P, adj_n, b, xh, sums, sumsq, Ev, Nv, NNZv);
  }
  {
    const float* g2    = (const float*)d_in[5 + 2 * 4];
    const float* beta2 = (const float*)d_in[6 + 2 * 4];
    finalize_bn_kernel<<<1, 128, 0, stream>>>(sums, sumsq, g2, beta2, aff_a, aff_d, Nv);
  }
  apply_affine_kernel<<<cdiv((long)Nv * 32, 256), 256, 0, stream>>>(
      xh, aff_a, aff_d, (float*)d_out, (long)Nv * 32);
}

// Round 10
// 671.751 us; speedup vs baseline: 2.2086x; 1.0463x over previous
//
#include <hip/hip_runtime.h>
#include <stdint.h>

#define DIM 128

static inline int cdiv(long a, long b) { return (int)((a + b - 1) / b); }

// clang ext-vector types: __builtin_nontemporal_* requires real vector types.
typedef float f32x4 __attribute__((ext_vector_type(4)));

// ---- bf16 pack/unpack (RNE) ----
__device__ __forceinline__ unsigned pk_bf16(float a, float b) {
  unsigned ua = __float_as_uint(a), ub = __float_as_uint(b);
  ua = (ua + 0x7FFFu + ((ua >> 16) & 1u)) >> 16;
  ub = (ub + 0x7FFFu + ((ub >> 16) & 1u)) >> 16;
  return ua | (ub << 16);
}
__device__ __forceinline__ float bf_lo(unsigned u) { return __uint_as_float(u << 16); }
__device__ __forceinline__ float bf_hi(unsigned u) { return __uint_as_float(u & 0xFFFF0000u); }

__device__ __forceinline__ void acc8(float4& a, const uint2* q) {
  a.x += ((bf_lo(q[0].x) + bf_lo(q[1].x)) + (bf_lo(q[2].x) + bf_lo(q[3].x))) +
         ((bf_lo(q[4].x) + bf_lo(q[5].x)) + (bf_lo(q[6].x) + bf_lo(q[7].x)));
  a.y += ((bf_hi(q[0].x) + bf_hi(q[1].x)) + (bf_hi(q[2].x) + bf_hi(q[3].x))) +
         ((bf_hi(q[4].x) + bf_hi(q[5].x)) + (bf_hi(q[6].x) + bf_hi(q[7].x)));
  a.z += ((bf_lo(q[0].y) + bf_lo(q[1].y)) + (bf_lo(q[2].y) + bf_lo(q[3].y))) +
         ((bf_lo(q[4].y) + bf_lo(q[5].y)) + (bf_lo(q[6].y) + bf_lo(q[7].y)));
  a.w += ((bf_hi(q[0].y) + bf_hi(q[1].y)) + (bf_hi(q[2].y) + bf_hi(q[3].y))) +
         ((bf_hi(q[4].y) + bf_hi(q[5].y)) + (bf_hi(q[6].y) + bf_hi(q[7].y)));
}

// Merged index-convert + degree-count.
__global__ __launch_bounds__(256) void count_kernel(
    const int* __restrict__ raw, int* __restrict__ src, int* __restrict__ edg,
    int* __restrict__ cnt, int E, int nnz) {
  bool is64;
  {
    int l = threadIdx.x & 63;
    int v = raw[2 * l + 1];               // high words if int64 (values < 2^31)
    unsigned long long m = __ballot(v == 0);
    is64 = (m == ~0ull);
  }
  int g = blockIdx.x * 256 + threadIdx.x;
  if (g < nnz) {
    int s = is64 ? raw[2 * g] : raw[g];
    int e = is64 ? raw[2 * (nnz + g)] : raw[nnz + g];
    src[g] = s;
    edg[g] = e;
    atomicAdd(&cnt[e], 1);
    atomicAdd(&cnt[E + s], 1);
  }
}

// ---- 3-kernel exclusive scan of cnt[0..M) into P[0..M], P[M]=total ----
__global__ __launch_bounds__(256) void scanA_kernel(
    const int* __restrict__ cnt, int* __restrict__ P, int* __restrict__ BS, int M) {
  __shared__ int lds[256];
  int t = threadIdx.x;
  long base = blockIdx.x * 1024L;
  int v[4], ts = 0;
#pragma unroll
  for (int j = 0; j < 4; ++j) {
    long i = base + t * 4 + j;
    v[j] = (i < M) ? cnt[i] : 0;
    ts += v[j];
  }
  lds[t] = ts;
  __syncthreads();
  for (int off = 1; off < 256; off <<= 1) {
    int x = (t >= off) ? lds[t - off] : 0;
    __syncthreads();
    lds[t] += x;
    __syncthreads();
  }
  int run = lds[t] - ts;  // exclusive base for this thread
#pragma unroll
  for (int j = 0; j < 4; ++j) {
    long i = base + t * 4 + j;
    if (i < M) P[i] = run;
    run += v[j];
  }
  if (t == 255) BS[blockIdx.x] = lds[255];
}

__global__ void scanB_kernel(int* __restrict__ BS, int* __restrict__ P,
                             int nblocks, int M) {
  if (threadIdx.x == 0) {
    int run = 0;
    for (int i = 0; i < nblocks; ++i) { int x = BS[i]; BS[i] = run; run += x; }
    P[M] = run;
  }
}

// scanC also zeroes cnt (saves the second memset launch before fill_adj).
__global__ __launch_bounds__(256) void scanC_kernel(
    int* __restrict__ P, const int* __restrict__ BS, int* __restrict__ cnt, int M) {
  long i = blockIdx.x * 256L + threadIdx.x;
  if (i < M) {
    P[i] += BS[i >> 10];
    cnt[i] = 0;
  }
}

// adj_e[P[e]..] = member nodes of edge e ; adj_n[P[E+i]-nnz..] = edges of node i
__global__ __launch_bounds__(256) void fill_adj_kernel(
    const int* __restrict__ src, const int* __restrict__ edg,
    const int* __restrict__ P, int* __restrict__ cnt,
    int* __restrict__ adj_e, int* __restrict__ adj_n, int E, int nnz) {
  int g = blockIdx.x * 256 + threadIdx.x;
  if (g < nnz) {
    int e = edg[g], s = src[g];
    int pe = P[e] + atomicAdd(&cnt[e], 1);
    adj_e[pe] = s;
    int pn = P[E + s] - nnz + atomicAdd(&cnt[E + s], 1);
    adj_n[pn] = e;
  }
}

// Single-block 1024-thread prep_w: computes the previous layer's BN affine
// inline from the running sums, scales W into Wp, reduces rvec = d@W via LDS
// (no atomics, no pre-memset), and ZEROES sums/sumsq for the upcoming
// node_gather (kills the per-layer memset launch).
__global__ __launch_bounds__(1024) void prep_w_kernel(
    const float* __restrict__ W, float* __restrict__ sums,
    float* __restrict__ sumsq, const float* __restrict__ gprev,
    const float* __restrict__ betaprev, float* __restrict__ Wp,
    float* __restrict__ rvec, int has_aff, float inv_n) {
  __shared__ float sa[DIM], sd[DIM];
  __shared__ float red[1024];
  int t = threadIdx.x;
  if (t < DIM) {
    float a = 1.0f, d = 0.0f;
    if (has_aff) {
      float mu = sums[t] * inv_n;
      float var = fmaf(sumsq[t], inv_n, -mu * mu);
      a = gprev[t] * rsqrtf(var + 1e-5f);
      d = fmaf(-mu, a, betaprev[t]);
    }
    sa[t] = a; sd[t] = d;
  }
  __syncthreads();
  if (t < DIM) { sums[t] = 0.f; sumsq[t] = 0.f; }  // reset for this layer
  int j = t & 127, grp = t >> 7;  // 8 groups x 128 channels
  float racc = 0.f;
  for (int c = grp; c < DIM; c += 8) {
    float w = W[c * DIM + j];
    Wp[c * DIM + j] = sa[c] * w;
    racc = fmaf(sd[c], w, racc);
  }
  red[t] = racc;
  __syncthreads();
  if (t < DIM) {
    float r = 0.f;
#pragma unroll
    for (int g2 = 0; g2 < 8; ++g2) r += red[j + g2 * 128];
    rvec[j] = r;
  }
}

// Layer-0 edge gather: fp32 node_attr directly (512 B rows), 8-chunk
// min-clamp + subtract-correction (no sentinel row available in the input;
// the serial correction tail amortizes over ~30-row edges).
__global__ __launch_bounds__(256) void edge_gather_f32_kernel(
    const float4* __restrict__ X4, const int* __restrict__ P,
    const int* __restrict__ adj_e, float* __restrict__ ag, int E) {
  int slot = threadIdx.x >> 5;
  int l = threadIdx.x & 31;
  int e = blockIdx.x * 8 + slot;
  if (e >= E) return;
  int p0 = P[e], p1 = P[e + 1];
  float4 a = {0.f, 0.f, 0.f, 0.f};
  int kl = p1 - 1;
  for (int k = p0; k < p1; k += 8) {
    int n0 = adj_e[min(k, kl)];
    int n1 = adj_e[min(k + 1, kl)];
    int n2 = adj_e[min(k + 2, kl)];
    int n3 = adj_e[min(k + 3, kl)];
    int n4 = adj_e[min(k + 4, kl)];
    int n5 = adj_e[min(k + 5, kl)];
    int n6 = adj_e[min(k + 6, kl)];
    int n7 = adj_e[min(k + 7, kl)];
    float4 q0 = X4[(size_t)n0 * 32 + l];
    float4 q1 = X4[(size_t)n1 * 32 + l];
    float4 q2 = X4[(size_t)n2 * 32 + l];
    float4 q3 = X4[(size_t)n3 * 32 + l];
    float4 q4 = X4[(size_t)n4 * 32 + l];
    float4 q5 = X4[(size_t)n5 * 32 + l];
    float4 q6 = X4[(size_t)n6 * 32 + l];
    float4 q7 = X4[(size_t)n7 * 32 + l];
    a.x += ((q0.x + q1.x) + (q2.x + q3.x)) + ((q4.x + q5.x) + (q6.x + q7.x));
    a.y += ((q0.y + q1.y) + (q2.y + q3.y)) + ((q4.y + q5.y) + (q6.y + q7.y));
    a.z += ((q0.z + q1.z) + (q2.z + q3.z)) + ((q4.z + q5.z) + (q6.z + q7.z));
    a.w += ((q0.w + q1.w) + (q2.w + q3.w)) + ((q4.w + q5.w) + (q6.w + q7.w));
  }
  int deg = p1 - p0;
  if (deg > 0) {
    int extra = ((deg + 7) & ~7) - deg;
    if (extra) {
      float4 ql = X4[(size_t)adj_e[kl] * 32 + l];
      float ex = (float)extra;
      a.x -= ex * ql.x; a.y -= ex * ql.y; a.z -= ex * ql.z; a.w -= ex * ql.w;
    }
  }
  float binv = (deg > 0) ? 1.0f / (float)deg : 0.0f;
  f32x4 o;
  o.x = a.x * binv; o.y = a.y * binv; o.z = a.z * binv; o.w = a.w * binv;
  __builtin_nontemporal_store(o, &((f32x4*)ag)[(size_t)e * 32 + l]);
}

// Layers 1,2: gather bf16 z rows, 16-wide chunk (mean edge size 30 -> 2
// rounds), SENTINEL selects (R9 lesson: min-clamp's correction tail is a
// serial dependent load; sentinel loads issue in parallel and row SENT=N
// is zero and L1-hot).
__global__ __launch_bounds__(256) void edge_gather_bf16_kernel(
    const uint2* __restrict__ xh, const int* __restrict__ P,
    const int* __restrict__ adj_e, float* __restrict__ ag, int E, int SENT) {
  int slot = threadIdx.x >> 5;
  int l = threadIdx.x & 31;
  int e = blockIdx.x * 8 + slot;
  if (e >= E) return;
  int p0 = P[e], p1 = P[e + 1];
  float4 a = {0.f, 0.f, 0.f, 0.f};
  int kl = p1 - 1;
  for (int k = p0; k < p1; k += 16) {
    int n[16];
    n[0] = adj_e[k];
#pragma unroll
    for (int j = 1; j < 16; ++j) n[j] = (k + j <= kl) ? adj_e[k + j] : SENT;
    uint2 q[16];
#pragma unroll
    for (int j = 0; j < 16; ++j) q[j] = xh[(size_t)n[j] * 32 + l];
    acc8(a, q);
    acc8(a, q + 8);
  }
  int deg = p1 - p0;
  float binv = (deg > 0) ? 1.0f / (float)deg : 0.0f;
  f32x4 o;
  o.x = a.x * binv; o.y = a.y * binv; o.z = a.z * binv; o.w = a.w * binv;
  __builtin_nontemporal_store(o, &((f32x4*)ag)[(size_t)e * 32 + l]);
}

// efh[E x 128 bf16] = (ag @ Wp + rvec), zeroed for empty edges (deg==0).
__global__ __launch_bounds__(256) void gemm128_kernel(
    const float* __restrict__ X, const float* __restrict__ Wp,
    const float* __restrict__ rvec, const int* __restrict__ Pdeg,
    unsigned* __restrict__ Yh, int nrows) {
  __shared__ float sW[32 * DIM];   // sW[kk*128 + j]
  __shared__ float sX[DIM * 36];   // sX[rr*36 + kk], 36 keeps 16B align + pad
  const int t = threadIdx.x;
  const int row0 = blockIdx.x * DIM;
  const int tx = t & 15, ty = t >> 4;
  const int col0 = tx * 8, lr0 = ty * 8;
  float acc[8][8];
#pragma unroll
  for (int i = 0; i < 8; ++i)
#pragma unroll
    for (int j = 0; j < 8; ++j) acc[i][j] = 0.0f;

  for (int kc = 0; kc < 4; ++kc) {
    __syncthreads();
    {
      const float4* W4 = (const float4*)(Wp + kc * 32 * DIM);
      float4* sW4 = (float4*)sW;
#pragma unroll
      for (int i = 0; i < 4; ++i) sW4[t + i * 256] = W4[t + i * 256];
    }
#pragma unroll
    for (int i = 0; i < 4; ++i) {
      int q = t + i * 256;            // 0..1023 float4 slots
      int rr = q >> 3, kq = q & 7;
      int gr = row0 + rr; if (gr >= nrows) gr = nrows - 1;  // stores are guarded
      float4 v = *(const float4*)&X[(size_t)gr * DIM + kc * 32 + kq * 4];
      *(float4*)&sX[rr * 36 + kq * 4] = v;
    }
    __syncthreads();
    for (int kk = 0; kk < 32; ++kk) {
      float4 w0 = *(const float4*)&sW[kk * DIM + col0];
      float4 w1 = *(const float4*)&sW[kk * DIM + col0 + 4];
      float wv[8] = {w0.x, w0.y, w0.z, w0.w, w1.x, w1.y, w1.z, w1.w};
      float xv[8];
#pragma unroll
      for (int i = 0; i < 8; ++i) xv[i] = sX[(lr0 + i) * 36 + kk];
#pragma unroll
      for (int i = 0; i < 8; ++i)
#pragma unroll
        for (int j = 0; j < 8; ++j) acc[i][j] = fmaf(xv[i], wv[j], acc[i][j]);
    }
  }
  float4 r0 = *(const float4*)&rvec[col0];
  float4 r1 = *(const float4*)&rvec[col0 + 4];
#pragma unroll
  for (int i = 0; i < 8; ++i) {
    int gr = row0 + lr0 + i;
    if (gr < nrows) {
      // empty segment must produce 0 (reference: Binv=0 ⇒ e_feat=0).
      float nz = (Pdeg[gr + 1] > Pdeg[gr]) ? 1.0f : 0.0f;
      float o0x = (acc[i][0] + r0.x) * nz, o0y = (acc[i][1] + r0.y) * nz;
      float o0z = (acc[i][2] + r0.z) * nz, o0w = (acc[i][3] + r0.w) * nz;
      float o1x = (acc[i][4] + r1.x) * nz, o1y = (acc[i][5] + r1.y) * nz;
      float o1z = (acc[i][6] + r1.z) * nz, o1w = (acc[i][7] + r1.w) * nz;
      uint4 st;
      st.x = pk_bf16(o0x, o0y);
      st.y = pk_bf16(o0z, o0w);
      st.z = pk_bf16(o1x, o1y);
      st.w = pk_bf16(o1z, o1w);
      *(uint4*)&Yh[(size_t)gr * 64 + (col0 >> 1)] = st;
    }
  }
}

// zh[i][c] = bf16(relu(Dinv_i * sum_{e ni i} ef[e][c] + b_c)), fused BN stats.
// R6's exact structure (best measured: 76us): single node per slot, sentinel
// clamp-8 (SENT row = zeros, L1-hot, loads all issue in parallel),
// grid-stride at 2048 blocks (R7: BN atomic fan-in scales with gridDim).
__global__ __launch_bounds__(256) void node_gather_kernel(
    const uint2* __restrict__ ef, const int* __restrict__ P,
    const int* __restrict__ adj_n, const float* __restrict__ b,
    uint2* __restrict__ zh, float* __restrict__ sum,
    float* __restrict__ sumsq, int E, int N, int nnz, int SENT) {
  __shared__ float lsum[DIM], lsumsq[DIM];
  int t = threadIdx.x;
  if (t < DIM) { lsum[t] = 0.f; lsumsq[t] = 0.f; }
  __syncthreads();
  int slot = t >> 5;
  int l = t & 31;
  float4 bc = ((const float4*)b)[l];
  float4 s1 = {0.f, 0.f, 0.f, 0.f}, s2 = {0.f, 0.f, 0.f, 0.f};
  for (int i = blockIdx.x * 8 + slot; i < N; i += gridDim.x * 8) {
    int p0 = P[E + i] - nnz, p1 = P[E + i + 1] - nnz;
    float4 a = {0.f, 0.f, 0.f, 0.f};
    int kl = p1 - 1;
    for (int k = p0; k < p1; k += 8) {
      int e0 = adj_n[k];
      int e1 = (k + 1 <= kl) ? adj_n[k + 1] : SENT;
      int e2 = (k + 2 <= kl) ? adj_n[k + 2] : SENT;
      int e3 = (k + 3 <= kl) ? adj_n[k + 3] : SENT;
      int e4 = (k + 4 <= kl) ? adj_n[k + 4] : SENT;
      int e5 = (k + 5 <= kl) ? adj_n[k + 5] : SENT;
      int e6 = (k + 6 <= kl) ? adj_n[k + 6] : SENT;
      int e7 = (k + 7 <= kl) ? adj_n[k + 7] : SENT;
      uint2 q[8];
      q[0] = ef[(size_t)e0 * 32 + l];
      q[1] = ef[(size_t)e1 * 32 + l];
      q[2] = ef[(size_t)e2 * 32 + l];
      q[3] = ef[(size_t)e3 * 32 + l];
      q[4] = ef[(size_t)e4 * 32 + l];
      q[5] = ef[(size_t)e5 * 32 + l];
      q[6] = ef[(size_t)e6 * 32 + l];
      q[7] = ef[(size_t)e7 * 32 + l];
      acc8(a, q);
    }
    int deg = p1 - p0;
    float dinv = (deg > 0) ? 1.0f / (float)deg : 0.0f;
    float4 v;
    v.x = fmaxf(fmaf(dinv, a.x, bc.x), 0.f);
    v.y = fmaxf(fmaf(dinv, a.y, bc.y), 0.f);
    v.z = fmaxf(fmaf(dinv, a.z, bc.z), 0.f);
    v.w = fmaxf(fmaf(dinv, a.w, bc.w), 0.f);
    uint2 o;
    o.x = pk_bf16(v.x, v.y);
    o.y = pk_bf16(v.z, v.w);
    zh[(size_t)i * 32 + l] = o;
    s1.x += v.x; s1.y += v.y; s1.z += v.z; s1.w += v.w;
    s2.x = fmaf(v.x, v.x, s2.x); s2.y = fmaf(v.y, v.y, s2.y);
    s2.z = fmaf(v.z, v.z, s2.z); s2.w = fmaf(v.w, v.w, s2.w);
  }
  int c0 = l * 4;
  atomicAdd(&lsum[c0 + 0], s1.x); atomicAdd(&lsum[c0 + 1], s1.y);
  atomicAdd(&lsum[c0 + 2], s1.z); atomicAdd(&lsum[c0 + 3], s1.w);
  atomicAdd(&lsumsq[c0 + 0], s2.x); atomicAdd(&lsumsq[c0 + 1], s2.y);
  atomicAdd(&lsumsq[c0 + 2], s2.z); atomicAdd(&lsumsq[c0 + 3], s2.w);
  __syncthreads();
  if (t < DIM) {
    atomicAdd(&sum[t], lsum[t]);
    atomicAdd(&sumsq[t], lsumsq[t]);
  }
}

// out = aff_a*zh + aff_d, with the BN-finalize FUSED: each block computes the
// affine from sums/sumsq in LDS (128 rsqrt per block — trivial, saves a
// dispatch + the aff_a/aff_d round-trip).
__global__ __launch_bounds__(256) void apply_affine_kernel(
    const uint2* __restrict__ zh, const float* __restrict__ sums,
    const float* __restrict__ sumsq, const float* __restrict__ g,
    const float* __restrict__ beta, float* __restrict__ out,
    long total4, float inv_n) {
  __shared__ float sa[DIM], sd[DIM];
  int t = threadIdx.x;
  if (t < DIM) {
    float mu = sums[t] * inv_n;
    float var = fmaf(sumsq[t], inv_n, -mu * mu);
    float a = g[t] * rsqrtf(var + 1e-5f);
    sa[t] = a;
    sd[t] = fmaf(-mu, a, beta[t]);
  }
  __syncthreads();
  long i = blockIdx.x * 256L + t;
  if (i >= total4) return;
  int c0 = (int)(i & 31) * 4;
  uint2 q = zh[i];
  f32x4 o;
  o.x = fmaf(sa[c0 + 0], bf_lo(q.x), sd[c0 + 0]);
  o.y = fmaf(sa[c0 + 1], bf_hi(q.x), sd[c0 + 1]);
  o.z = fmaf(sa[c0 + 2], bf_lo(q.y), sd[c0 + 2]);
  o.w = fmaf(sa[c0 + 3], bf_hi(q.y), sd[c0 + 3]);
  __builtin_nontemporal_store(o, &((f32x4*)out)[i]);
}

extern "C" void kernel_launch(void* const* d_in, const int* in_sizes, int n_in,
                              void* d_out, int out_size, void* d_ws, size_t ws_size,
                              hipStream_t stream) {
  const int NNZv = in_sizes[0] / 2;
  const int Nv   = in_sizes[1] / DIM;
  const int Ev   = in_sizes[2] / DIM;
  const int* eidx_raw = (const int*)d_in[0];
  const float* node_attr = (const float*)d_in[1];

  // ---- workspace layout (~47 MB total) ----
  float* bufE  = (float*)d_ws;                 // E*128 f32 (ag)
  float* Wp    = bufE + (size_t)Ev * DIM;      // 128*128
  float* rvec  = Wp + DIM * DIM;               // 128
  float* sums  = rvec + 128;                   // 128
  float* sumsq = sums + 128;                   // 128
  float* aff_a = sumsq + 128;                  // 128 (unused, kept for layout)
  float* aff_d = aff_a + 128;                  // 128
  int* src   = (int*)(aff_d + 128);            // NNZ
  int* edg   = src + NNZv;                     // NNZ
  int* cnt   = edg + NNZv;                     // E+N (padded to x4)
  int* P     = cnt + (((size_t)Ev + Nv + 3) & ~(size_t)3);  // E+N+1 (padded)
  int* BS    = P + (((size_t)Ev + Nv + 1 + 3) & ~(size_t)3); // <=256 block sums
  int* adj_e = BS + 256;                       // NNZ
  int* adj_n = adj_e + NNZv;                   // NNZ
  unsigned* efh = (unsigned*)src;              // (E+1)*64 uints (bf16 ef rows)
  uint2* xh = (uint2*)(adj_n + NNZv);          // (N+1)*32 uint2 (bf16 z)

  const int M = Ev + Nv;
  const int nbA = cdiv(M, 1024);
  const float inv_n = 1.0f / (float)Nv;

  hipMemsetAsync(cnt, 0, (size_t)M * 4, stream);
  count_kernel<<<cdiv(NNZv, 256), 256, 0, stream>>>(eidx_raw, src, edg, cnt, Ev, NNZv);
  scanA_kernel<<<nbA, 256, 0, stream>>>(cnt, P, BS, M);
  scanB_kernel<<<1, 64, 0, stream>>>(BS, P, nbA, M);
  scanC_kernel<<<cdiv(M, 256), 256, 0, stream>>>(P, BS, cnt, M);
  fill_adj_kernel<<<cdiv(NNZv, 256), 256, 0, stream>>>(src, edg, P, cnt, adj_e, adj_n, Ev, NNZv);
  // zero sentinel rows (edge row E in efh, node row N in xh), once
  hipMemsetAsync(efh + (size_t)Ev * 64, 0, 256, stream);
  hipMemsetAsync(xh + (size_t)Nv * 32, 0, 256, stream);

  for (int l = 0; l < 3; ++l) {
    const float* W     = (const float*)d_in[3 + l * 4];
    const float* b     = (const float*)d_in[4 + l * 4];
    const float* gprev    = (const float*)d_in[5 + (l > 0 ? l - 1 : 0) * 4];
    const float* betaprev = (const float*)d_in[6 + (l > 0 ? l - 1 : 0) * 4];

    prep_w_kernel<<<1, 1024, 0, stream>>>(W, sums, sumsq, gprev, betaprev,
                                          Wp, rvec, l > 0 ? 1 : 0, inv_n);
    if (l == 0)
      edge_gather_f32_kernel<<<cdiv(Ev, 8), 256, 0, stream>>>(
          (const float4*)node_attr, P, adj_e, bufE, Ev);
    else
      edge_gather_bf16_kernel<<<cdiv(Ev, 8), 256, 0, stream>>>(
          xh, P, adj_e, bufE, Ev, Nv);
    gemm128_kernel<<<cdiv(Ev, DIM), 256, 0, stream>>>(bufE, Wp, rvec, P, efh, Ev);
    node_gather_kernel<<<2048, 256, 0, stream>>>(
        (const uint2*)efh, P, adj_n, b, xh, sums, sumsq, Ev, Nv, NNZv, Ev);
  }
  {
    const float* g2    = (const float*)d_in[5 + 2 * 4];
    const float* beta2 = (const float*)d_in[6 + 2 * 4];
    apply_affine_kernel<<<cdiv((long)Nv * 32, 256), 256, 0, stream>>>(
        xh, sums, sumsq, g2, beta2, (float*)d_out, (long)Nv * 32, inv_n);
  }
}